// Round 7
// baseline (11466.342 us; speedup 1.0000x reference)
//
#include <hip/hip_runtime.h>
#include <hip/hip_cooperative_groups.h>
#include <math.h>

namespace cgns = cooperative_groups;

#define N_NODES 50000
#define N_EDGES 800000
#define NHID    128
#define NOUT    40
#define NLAYERS 4
#define CG_ITERS 10
#define HSTEP   0.1f
#define EPS_BN  1e-5f

#define NB   (N_NODES * NHID)     /* 6,400,000 floats */
#define NB4  (NB / 4)             /* 1,600,000 float4 */

#define EW_BLOCKS   2048
#define SPMV_BLOCKS 2048
#define ATTN_BLOCKS 2048
#define SCAN_BLOCKS 196           /* ceil(50000/256) */

/* scalar slot layout (floats): all DIRECT dot values (no algebraic carry) */
#define SLOT_RR0   0
#define SLOT_PLP   1    /* [10] */
#define SLOT_NR    11   /* [10] */

__device__ __forceinline__ float wred64(float v) {
    v += __shfl_xor(v, 32, 64);
    v += __shfl_xor(v, 16, 64);
    v += __shfl_xor(v, 8, 64);
    v += __shfl_xor(v, 4, 64);
    v += __shfl_xor(v, 2, 64);
    v += __shfl_xor(v, 1, 64);
    return v;
}

__device__ __forceinline__ int wscan64(int v, int lane) {
    int incl = v;
    #pragma unroll
    for (int off = 1; off < 64; off <<= 1) {
        int t = __shfl_up(incl, off, 64);
        if (lane >= off) incl += t;
    }
    return incl;
}

/* ---------------- shared CG loop bodies (used by coop kernel AND fallback kernels) ---------------- */

/* combine: Tr = elu(bn(T1 + h*dT)); P=X=R=Tr; returns partial RR0.
   R may alias T1 (same-index in-place). */
__device__ __forceinline__ float body_combine(
    const float* T1v, const float* __restrict__ M1v, const float* M2v,
    const float* __restrict__ bg, const float* __restrict__ bb,
    const float* __restrict__ bm, const float* __restrict__ bv,
    float* P, float* X, float* R, int gid, int gsize)
{
    float rr0 = 0.f;
    for (int i = gid; i < NB4; i += gsize) {
        float4 t1 = ((const float4*)T1v)[i];
        float4 m1 = ((const float4*)M1v)[i];
        float4 m2 = ((const float4*)M2v)[i];
        int chb = (i * 4) & 127;
        float tt[4] = {t1.x, t1.y, t1.z, t1.w};
        float a1[4] = {m1.x, m1.y, m1.z, m1.w};
        float a2[4] = {m2.x, m2.y, m2.z, m2.w};
        float o[4];
        #pragma unroll
        for (int k = 0; k < 4; k++) {
            float cl = fminf(fmaxf(a2[k], -1.f), 1.f);
            float x = tt[k] + HSTEP * (a1[k] + tt[k] * cl);
            int ch = chb + k;
            float xb = (x - bm[ch]) * rsqrtf(bv[ch] + EPS_BN) * bg[ch] + bb[ch];
            o[k] = xb > 0.f ? xb : expm1f(xb);
            rr0 += o[k] * o[k];
        }
        float4 o4 = make_float4(o[0], o[1], o[2], o[3]);
        ((float4*)P)[i] = o4;
        ((float4*)X)[i] = o4;
        ((float4*)R)[i] = o4;
    }
    return rr0;
}

/* spmv: LP = P + h*Kd*(P + L@P); returns partial P.LP. Wave-per-row, float2 lanes. */
__device__ __forceinline__ float body_spmv(
    const int* __restrict__ rowptr, const int* __restrict__ ecol, const float* __restrict__ ewt,
    const float2* __restrict__ P2, float2* __restrict__ LP2, float2 kd2,
    int r0, int rstride, int lane)
{
    float pPLP = 0.f;
    for (int r = r0; r < N_NODES; r += rstride) {
        int e0 = rowptr[r], e1 = rowptr[r + 1];
        float ax = 0.f, ay = 0.f;
        int e = e0;
        for (; e + 8 <= e1; e += 8) {
            int   c0 = ecol[e],     c1 = ecol[e + 1], c2 = ecol[e + 2], c3 = ecol[e + 3];
            int   c4 = ecol[e + 4], c5 = ecol[e + 5], c6 = ecol[e + 6], c7 = ecol[e + 7];
            float w0 = ewt[e],     w1 = ewt[e + 1], w2 = ewt[e + 2], w3 = ewt[e + 3];
            float w4 = ewt[e + 4], w5 = ewt[e + 5], w6 = ewt[e + 6], w7 = ewt[e + 7];
            float2 p0 = P2[(size_t)c0 * 64 + lane];
            float2 p1 = P2[(size_t)c1 * 64 + lane];
            float2 p2 = P2[(size_t)c2 * 64 + lane];
            float2 p3 = P2[(size_t)c3 * 64 + lane];
            float2 p4 = P2[(size_t)c4 * 64 + lane];
            float2 p5 = P2[(size_t)c5 * 64 + lane];
            float2 p6 = P2[(size_t)c6 * 64 + lane];
            float2 p7 = P2[(size_t)c7 * 64 + lane];
            ax += w0 * p0.x + w1 * p1.x + w2 * p2.x + w3 * p3.x
                + w4 * p4.x + w5 * p5.x + w6 * p6.x + w7 * p7.x;
            ay += w0 * p0.y + w1 * p1.y + w2 * p2.y + w3 * p3.y
                + w4 * p4.y + w5 * p5.y + w6 * p6.y + w7 * p7.y;
        }
        for (; e < e1; ++e) {
            int c = ecol[e]; float w = ewt[e];
            float2 p = P2[(size_t)c * 64 + lane];
            ax += w * p.x; ay += w * p.y;
        }
        size_t idx = (size_t)r * 64 + lane;
        float2 pv = P2[idx];
        float2 lp;
        lp.x = pv.x + HSTEP * (kd2.x * (pv.x + ax));
        lp.y = pv.y + HSTEP * (kd2.y * (pv.y + ay));
        LP2[idx] = lp;
        pPLP += pv.x * lp.x + pv.y * lp.y;
    }
    return pPLP;
}

/* X += a*P; R -= a*LP; returns partial DIRECT nr = sum(Rnew^2). */
__device__ __forceinline__ float body_xr(
    float* X, const float* __restrict__ P, const float* __restrict__ LP, float* R,
    float alpha, int gid, int gsize)
{
    float pNR = 0.f;
    for (int i = gid; i < NB4; i += gsize) {
        float4 x = ((const float4*)X)[i];
        float4 p = ((const float4*)P)[i];
        float4 lp = ((const float4*)LP)[i];
        float4 r = ((const float4*)R)[i];
        x.x += alpha * p.x; x.y += alpha * p.y; x.z += alpha * p.z; x.w += alpha * p.w;
        r.x -= alpha * lp.x; r.y -= alpha * lp.y; r.z -= alpha * lp.z; r.w -= alpha * lp.w;
        ((float4*)X)[i] = x;
        ((float4*)R)[i] = r;
        pNR += r.x * r.x + r.y * r.y + r.z * r.z + r.w * r.w;
    }
    return pNR;
}

__device__ __forceinline__ void body_pupd(
    const float* __restrict__ R, float* P, float beta, int gid, int gsize)
{
    for (int i = gid; i < NB4; i += gsize) {
        float4 r = ((const float4*)R)[i];
        float4 p = ((const float4*)P)[i];
        p.x = r.x + beta * p.x; p.y = r.y + beta * p.y;
        p.z = r.z + beta * p.z; p.w = r.w + beta * p.w;
        ((float4*)P)[i] = p;
    }
}

/* ---------------- CSR build ---------------- */

__global__ void k_zero_i32(int* p, int n) {
    int i = blockIdx.x * blockDim.x + threadIdx.x;
    int stride = gridDim.x * blockDim.x;
    for (; i < n; i += stride) p[i] = 0;
}

__global__ void k_count(const int* __restrict__ row, const int* __restrict__ col, int* __restrict__ deg) {
    int e = blockIdx.x * 256 + threadIdx.x;
    if (e < N_EDGES) {
        int r = row[e], c = col[e];
        if (r != c) atomicAdd(&deg[r], 1);
    }
}

__global__ __launch_bounds__(256) void k_scan1(const int* __restrict__ deg,
                                               int* __restrict__ rowptr, int* __restrict__ blksum) {
    __shared__ int wsum[4];
    int tid = threadIdx.x, lane = tid & 63, wid = tid >> 6;
    int i = blockIdx.x * 256 + tid;
    int v = (i < N_NODES) ? deg[i] : 0;
    int incl = wscan64(v, lane);
    if (lane == 63) wsum[wid] = incl;
    __syncthreads();
    int wpre = 0;
    for (int w = 0; w < wid; w++) wpre += wsum[w];
    incl += wpre;
    if (i < N_NODES) rowptr[i + 1] = incl;
    if (tid == 255) blksum[blockIdx.x] = incl;
}

__global__ __launch_bounds__(256) void k_scan2(const int* __restrict__ blksum, int* __restrict__ blkoff) {
    __shared__ int wsum[4];
    int tid = threadIdx.x, lane = tid & 63, wid = tid >> 6;
    int v = (tid < SCAN_BLOCKS) ? blksum[tid] : 0;
    int incl = wscan64(v, lane);
    if (lane == 63) wsum[wid] = incl;
    __syncthreads();
    int wpre = 0;
    for (int w = 0; w < wid; w++) wpre += wsum[w];
    incl += wpre;
    if (tid < SCAN_BLOCKS) blkoff[tid] = incl - v;
}

__global__ __launch_bounds__(256) void k_scan3(const int* __restrict__ deg, const int* __restrict__ blkoff,
                                               int* __restrict__ rowptr, float* __restrict__ dinv,
                                               int* __restrict__ cursor) {
    int i = blockIdx.x * 256 + threadIdx.x;
    if (i == 0) rowptr[0] = 0;
    if (i < N_NODES) {
        int incl = rowptr[i + 1] + blkoff[blockIdx.x];
        rowptr[i + 1] = incl;
        int d = deg[i];
        cursor[i] = incl - d;
        dinv[i] = (d > 0) ? rsqrtf((float)d) : 0.0f;
    }
}

__global__ void k_scatter(const int* __restrict__ row, const int* __restrict__ col,
                          const float* __restrict__ dinv, int* __restrict__ cursor,
                          int* __restrict__ ecol, float* __restrict__ ew) {
    int e = blockIdx.x * 256 + threadIdx.x;
    if (e < N_EDGES) {
        int r = row[e], c = col[e];
        if (r != c) {
            int p = atomicAdd(&cursor[r], 1);
            ecol[p] = c;
            ew[p] = -dinv[r] * dinv[c];
        }
    }
}

/* ---------------- attention precompute ---------------- */

__global__ void k_mmat(const float* __restrict__ Wq, const float* __restrict__ Wk, float* __restrict__ M) {
    int h1 = blockIdx.x, h2 = threadIdx.x;
    float s = 0.f;
    for (int d = 0; d < 128; ++d) s += Wq[d * 128 + h1] * Wk[d * 128 + h2];
    M[h1 * 128 + h2] = s;
}

__global__ void k_uv(const float* __restrict__ Wq, const float* __restrict__ Wk,
                     const float* __restrict__ bq, const float* __restrict__ bk,
                     float* __restrict__ u, float* __restrict__ v, float* __restrict__ c0) {
    int h = threadIdx.x;
    float su = 0.f, sv = 0.f;
    for (int d = 0; d < 128; ++d) {
        su += Wk[d * 128 + h] * bq[d];
        sv += Wq[d * 128 + h] * bk[d];
    }
    u[h] = su; v[h] = sv;
    if (h == 0) {
        float s = 0.f;
        for (int d = 0; d < 128; ++d) s += bq[d] * bk[d];
        *c0 = s;
    }
}

/* ---------------- GEMM ---------------- */

__global__ __launch_bounds__(256) void k_gemm128(
    const float* __restrict__ A, const float* __restrict__ W, const float* __restrict__ bias,
    float* __restrict__ C, int M, int epi, int accflag,
    const float* __restrict__ bng, const float* __restrict__ bnb,
    const float* __restrict__ bnm, const float* __restrict__ bnv)
{
    __shared__ float Wt[128][132];
    int tid = threadIdx.x;
    for (int i = tid; i < 128 * 128; i += 256) {
        int c = i >> 7, k = i & 127;
        Wt[k][c] = W[i];
    }
    __syncthreads();

    int tx = tid & 15, ty = tid >> 4;
    int r0 = blockIdx.x * 64 + ty * 4;
    int c0 = tx * 8;
    if (r0 >= M) return;

    float acc[4][8];
    #pragma unroll
    for (int i = 0; i < 4; i++)
        #pragma unroll
        for (int j = 0; j < 8; j++) acc[i][j] = 0.f;

    for (int k = 0; k < 128; k += 4) {
        float4 av[4];
        #pragma unroll
        for (int rr = 0; rr < 4; ++rr)
            av[rr] = *(const float4*)(A + (size_t)(r0 + rr) * 128 + k);
        #pragma unroll
        for (int kk = 0; kk < 4; ++kk) {
            float4 w0 = *(const float4*)&Wt[k + kk][c0];
            float4 w1 = *(const float4*)&Wt[k + kk][c0 + 4];
            #pragma unroll
            for (int rr = 0; rr < 4; ++rr) {
                float a = (kk == 0) ? av[rr].x : (kk == 1) ? av[rr].y : (kk == 2) ? av[rr].z : av[rr].w;
                acc[rr][0] += a * w0.x; acc[rr][1] += a * w0.y;
                acc[rr][2] += a * w0.z; acc[rr][3] += a * w0.w;
                acc[rr][4] += a * w1.x; acc[rr][5] += a * w1.y;
                acc[rr][6] += a * w1.z; acc[rr][7] += a * w1.w;
            }
        }
    }

    #pragma unroll
    for (int rr = 0; rr < 4; ++rr) {
        int r = r0 + rr;
        float out[8];
        #pragma unroll
        for (int j = 0; j < 8; j++) {
            int c = c0 + j;
            float x = acc[rr][j];
            if (bias) x += bias[c];
            if (accflag) x += C[(size_t)r * 128 + c];
            if (epi) {
                float xb = (x - bnm[c]) * rsqrtf(bnv[c] + EPS_BN) * bng[c] + bnb[c];
                x = (epi == 1) ? (xb > 0.f ? xb : expm1f(xb)) : (xb > 0.f ? xb : 0.f);
            }
            out[j] = x;
        }
        *(float4*)(C + (size_t)r * 128 + c0)     = make_float4(out[0], out[1], out[2], out[3]);
        *(float4*)(C + (size_t)r * 128 + c0 + 4) = make_float4(out[4], out[5], out[6], out[7]);
    }
}

/* ---------------- Kclose ---------------- */

__global__ __launch_bounds__(256) void k_close(const float* __restrict__ A, const float* __restrict__ W,
                                               const float* __restrict__ bias, float* __restrict__ out) {
    __shared__ float Wl[40 * 128];
    int tid = threadIdx.x;
    for (int i = tid; i < 40 * 128; i += 256) Wl[i] = W[i];
    __syncthreads();
    int n = blockIdx.x * 256 + tid;
    if (n >= N_NODES) return;
    float acc[40];
    #pragma unroll
    for (int c = 0; c < 40; c++) acc[c] = bias[c];
    for (int k = 0; k < 128; k += 4) {
        float4 a = *(const float4*)(A + (size_t)n * 128 + k);
        #pragma unroll
        for (int c = 0; c < 40; c++) {
            float4 w = *(const float4*)&Wl[c * 128 + k];
            acc[c] += a.x * w.x + a.y * w.y + a.z * w.z + a.w * w.w;
        }
    }
    #pragma unroll
    for (int c = 0; c < 40; c++) out[(size_t)n * 40 + c] = acc[c];
}

/* ---------------- attention ---------------- */

__global__ void k_zero16(float* p) {
    if (threadIdx.x < 16) p[threadIdx.x] = 0.f;
}

__global__ __launch_bounds__(256) void k_attn(
    const float* __restrict__ h0, const float* __restrict__ h1,
    const float* __restrict__ h2, const float* __restrict__ h3,
    const float* __restrict__ g0, const float* __restrict__ g1,
    const float* __restrict__ g2, const float* __restrict__ g3,
    const float* __restrict__ u, const float* __restrict__ v,
    const float* __restrict__ c0p, const float* __restrict__ mha,
    float* __restrict__ Cm)
{
    int tid = threadIdx.x;
    int lane = tid & 63, wid = tid >> 6;
    const float* hp[4] = {h0, h1, h2, h3};
    const float* gp[4] = {g0, g1, g2, g3};
    float uu0 = u[lane], uu1 = u[lane + 64];
    float vv0 = v[lane], vv1 = v[lane + 64];
    float c0v = *c0p;
    float rf = mha[0]; rf = rf > 0.f ? rf : 0.f;
    const float scale = 0.08838834764831845f; /* 128^-0.5 */

    float tacc = 0.f;    /* meaningful in lanes 0..15 */
    int totalWaves = gridDim.x * 4;
    for (int n = blockIdx.x * 4 + wid; n < N_NODES; n += totalWaves) {
        float a0[4], a1[4], gg0[4], gg1[4];
        size_t base = (size_t)n * 128 + lane;
        #pragma unroll
        for (int o = 0; o < 4; o++) {
            a0[o] = hp[o][base];  a1[o] = hp[o][base + 64];
            gg0[o] = gp[o][base]; gg1[o] = gp[o][base + 64];
        }
        float s[4][4], pu[4], pv[4];
        #pragma unroll
        for (int i = 0; i < 4; i++) {
            pu[i] = wred64(uu0 * a0[i] + uu1 * a1[i]);
            pv[i] = wred64(vv0 * a0[i] + vv1 * a1[i]);
            #pragma unroll
            for (int j = 0; j < 4; j++)
                s[i][j] = wred64(a0[i] * gg0[j] + a1[i] * gg1[j]);
        }
        #pragma unroll
        for (int i = 0; i < 4; i++)
            #pragma unroll
            for (int j = 0; j < 4; j++)
                s[i][j] = scale * (s[i][j] + pu[j] + pv[i] + c0v);

        if (lane < 16) {
            int i = lane >> 2, j = lane & 3;
            float m = fmaxf(fmaxf(s[i][0], s[i][1]), fmaxf(s[i][2], s[i][3]));
            float den = expf(s[i][0] - m) + expf(s[i][1] - m) + expf(s[i][2] - m) + expf(s[i][3] - m);
            float attn = expf(s[i][j] - m) / den;
            tacc += logf(attn * rf + 1e-4f);
        }
    }
    __shared__ float accum[4][16];
    if (lane < 16) accum[wid][lane] = tacc;
    __syncthreads();
    if (tid < 16)
        atomicAdd(&Cm[tid], accum[0][tid] + accum[1][tid] + accum[2][tid] + accum[3][tid]);
}

__global__ void k_cvec(const float* __restrict__ Cm, float* __restrict__ c) {
    if (threadIdx.x == 0) {
        float cm[16];
        for (int i = 0; i < 16; i++) cm[i] = Cm[i] / (float)N_NODES;
        float cc[4];
        for (int j = 0; j < 4; j++) cc[j] = 0.5f * (cm[12 + j] + cm[j * 4 + 3]);
        float s = cc[0] + cc[1] + cc[2] + cc[3];
        for (int j = 0; j < 4; j++) c[j] = cc[j] / s;
    }
}

__global__ __launch_bounds__(256) void k_t1(
    const float* __restrict__ h0, const float* __restrict__ h1,
    const float* __restrict__ h2, const float* __restrict__ h3,
    const float* __restrict__ c, float* __restrict__ T1)
{
    float c0 = c[0], c1 = c[1], c2 = c[2], c3 = c[3];
    int stride = gridDim.x * blockDim.x;
    for (int i = blockIdx.x * blockDim.x + threadIdx.x; i < NB4; i += stride) {
        float4 x0 = ((const float4*)h0)[i];
        float4 x1 = ((const float4*)h1)[i];
        float4 x2 = ((const float4*)h2)[i];
        float4 x3 = ((const float4*)h3)[i];
        float4 o;
        o.x = c0 * x0.x + c1 * x1.x + c2 * x2.x + c3 * x3.x;
        o.y = c0 * x0.y + c1 * x1.y + c2 * x2.y + c3 * x3.y;
        o.z = c0 * x0.z + c1 * x1.z + c2 * x2.z + c3 * x3.z;
        o.w = c0 * x0.w + c1 * x1.w + c2 * x2.w + c3 * x3.w;
        ((float4*)T1)[i] = o;
    }
}

/* ---------------- cooperative CG: combine + full CG loop, DIRECT dots only ---------------- */

__global__ __launch_bounds__(256) void k_cg(
    const float* T1v, const float* __restrict__ M1v, const float* M2v,
    const float* __restrict__ bg, const float* __restrict__ bb,
    const float* __restrict__ bm, const float* __restrict__ bv,
    const float* __restrict__ Kap,
    const int* __restrict__ rowptr, const int* __restrict__ ecol, const float* __restrict__ ewt,
    float* P, float* X, float* R, float* LP,
    float* scal)
{
    cgns::grid_group grid = cgns::this_grid();
    int tid = threadIdx.x, lane = tid & 63, wid = tid >> 6;
    int gid = blockIdx.x * 256 + tid;
    int gsize = gridDim.x * 256;
    __shared__ float red[8];

    /* phase 0: combine + P=X=R=Tr + direct RR0 */
    float rr0 = body_combine(T1v, M1v, M2v, bg, bb, bm, bv, P, X, R, gid, gsize);
    rr0 = wred64(rr0);
    if (lane == 0) red[wid] = rr0;
    __syncthreads();
    if (tid == 0) atomicAdd(&scal[SLOT_RR0], red[0] + red[1] + red[2] + red[3]);
    grid.sync();

    float RRcur = __hip_atomic_load(&scal[SLOT_RR0], __ATOMIC_RELAXED, __HIP_MEMORY_SCOPE_AGENT);
    float2 kd2 = ((const float2*)Kap)[lane];
    kd2.x = fminf(fmaxf(kd2.x, 0.f), 1.f);
    kd2.y = fminf(fmaxf(kd2.y, 0.f), 1.f);
    int totalWaves = gridDim.x * 4;

    for (int it = 0; it < CG_ITERS; ++it) {
        /* spmv phase: LP + direct PLP */
        float pPLP = body_spmv(rowptr, ecol, ewt, (const float2*)P, (float2*)LP, kd2,
                               blockIdx.x * 4 + wid, totalWaves, lane);
        pPLP = wred64(pPLP);
        __syncthreads();
        if (lane == 0) red[wid] = pPLP;
        __syncthreads();
        if (tid == 0) atomicAdd(&scal[SLOT_PLP + it], red[0] + red[1] + red[2] + red[3]);
        grid.sync();

        /* X,R update + DIRECT nr */
        float PLP = __hip_atomic_load(&scal[SLOT_PLP + it], __ATOMIC_RELAXED, __HIP_MEMORY_SCOPE_AGENT);
        float alpha = RRcur / (PLP + 1e-6f);
        float pNR = body_xr(X, P, LP, R, alpha, gid, gsize);
        pNR = wred64(pNR);
        __syncthreads();
        if (lane == 0) red[4 + wid] = pNR;
        __syncthreads();
        if (tid == 0) atomicAdd(&scal[SLOT_NR + it], red[4] + red[5] + red[6] + red[7]);
        grid.sync();

        /* P update / uniform convergence break (P frozen exactly as reference's done2) */
        float nr = __hip_atomic_load(&scal[SLOT_NR + it], __ATOMIC_RELAXED, __HIP_MEMORY_SCOPE_AGENT);
        if (nr < 1e-5f) break;      /* uniform: identical loads + identical f32 compare */
        float beta = nr / (RRcur + 1e-6f);
        body_pupd(R, P, beta, gid, gsize);
        RRcur = nr;
        grid.sync();
    }
}

/* ---------------- fallback (non-cooperative) CG kernels, same bodies ---------------- */

__global__ __launch_bounds__(256) void f_combine(
    const float* T1v, const float* __restrict__ M1v, const float* M2v,
    const float* __restrict__ bg, const float* __restrict__ bb,
    const float* __restrict__ bm, const float* __restrict__ bv,
    float* P, float* X, float* R, float* scal, int* doneArr)
{
    int tid = threadIdx.x, lane = tid & 63, wid = tid >> 6;
    if (blockIdx.x == 0 && tid == 0) doneArr[0] = 0;
    int gid = blockIdx.x * 256 + tid;
    int gsize = gridDim.x * 256;
    float rr0 = body_combine(T1v, M1v, M2v, bg, bb, bm, bv, P, X, R, gid, gsize);
    rr0 = wred64(rr0);
    __shared__ float red[4];
    if (lane == 0) red[wid] = rr0;
    __syncthreads();
    if (tid == 0) atomicAdd(&scal[SLOT_RR0], red[0] + red[1] + red[2] + red[3]);
}

__global__ __launch_bounds__(256) void f_spmv(
    const int* __restrict__ rowptr, const int* __restrict__ ecol, const float* __restrict__ ewt,
    const float* __restrict__ P, const float* __restrict__ Kap,
    float* __restrict__ LP, float* __restrict__ scal, const int* __restrict__ doneArr, int it)
{
    if (doneArr[it]) return;
    int tid = threadIdx.x, lane = tid & 63, wid = tid >> 6;
    float2 kd2 = ((const float2*)Kap)[lane];
    kd2.x = fminf(fmaxf(kd2.x, 0.f), 1.f);
    kd2.y = fminf(fmaxf(kd2.y, 0.f), 1.f);
    float pPLP = body_spmv(rowptr, ecol, ewt, (const float2*)P, (float2*)LP, kd2,
                           blockIdx.x * 4 + wid, gridDim.x * 4, lane);
    pPLP = wred64(pPLP);
    __shared__ float red[4];
    if (lane == 0) red[wid] = pPLP;
    __syncthreads();
    if (tid == 0) atomicAdd(&scal[SLOT_PLP + it], red[0] + red[1] + red[2] + red[3]);
}

__global__ __launch_bounds__(256) void f_xr(
    float* X, const float* __restrict__ P, const float* __restrict__ LP, float* R,
    float* __restrict__ scal, const int* __restrict__ doneArr, int it)
{
    if (doneArr[it]) return;
    float RR = (it == 0) ? scal[SLOT_RR0] : scal[SLOT_NR + it - 1];
    float alpha = RR / (scal[SLOT_PLP + it] + 1e-6f);
    int gid = blockIdx.x * 256 + threadIdx.x;
    float pNR = body_xr(X, P, LP, R, alpha, gid, gridDim.x * 256);
    pNR = wred64(pNR);
    __shared__ float red[4];
    int lane = threadIdx.x & 63, wid = threadIdx.x >> 6;
    if (lane == 0) red[wid] = pNR;
    __syncthreads();
    if (threadIdx.x == 0) atomicAdd(&scal[SLOT_NR + it], red[0] + red[1] + red[2] + red[3]);
}

__global__ __launch_bounds__(256) void f_pupd(
    const float* __restrict__ R, float* P,
    const float* __restrict__ scal, int* doneArr, int it)
{
    if (doneArr[it]) { if (blockIdx.x == 0 && threadIdx.x == 0) doneArr[it + 1] = 1; return; }
    float nr = scal[SLOT_NR + it];
    int d2 = (nr < 1e-5f);
    if (blockIdx.x == 0 && threadIdx.x == 0) doneArr[it + 1] = d2;
    if (d2) return;
    float RR = (it == 0) ? scal[SLOT_RR0] : scal[SLOT_NR + it - 1];
    float beta = nr / (RR + 1e-6f);
    body_pupd(R, P, beta, blockIdx.x * 256 + threadIdx.x, gridDim.x * 256);
}

/* ---------------- host ---------------- */

extern "C" void kernel_launch(void* const* d_in, const int* in_sizes, int n_in,
                              void* d_out, int out_size, void* d_ws, size_t ws_size,
                              hipStream_t stream) {
    (void)in_sizes; (void)n_in; (void)out_size; (void)ws_size;

    const float* T      = (const float*)d_in[0];
    const int*   EI     = (const int*)d_in[1];
    const float* KopenW = (const float*)d_in[2];
    const float* Kopenb = (const float*)d_in[3];
    const float* bnOg   = (const float*)d_in[4];
    const float* bnOb   = (const float*)d_in[5];
    const float* bnOm   = (const float*)d_in[6];
    const float* bnOv   = (const float*)d_in[7];
    const float* convW  = (const float*)d_in[8];
    const float* convb  = (const float*)d_in[9];
    const float* bnAg   = (const float*)d_in[10];
    const float* bnAb   = (const float*)d_in[11];
    const float* bnAm   = (const float*)d_in[12];
    const float* bnAv   = (const float*)d_in[13];
    const float* Wq     = (const float*)d_in[14];
    const float* bq     = (const float*)d_in[15];
    const float* Wk     = (const float*)d_in[16];
    const float* bk     = (const float*)d_in[17];
    const float* mha    = (const float*)d_in[18];
    const float* KR1W   = (const float*)d_in[19];
    const float* KR1b   = (const float*)d_in[20];
    const float* KR2W   = (const float*)d_in[21];
    const float* KR2b   = (const float*)d_in[22];
    const float* KRU0W  = (const float*)d_in[23];
    const float* KRU0b  = (const float*)d_in[24];
    const float* bng    = (const float*)d_in[25];
    const float* bnbb   = (const float*)d_in[26];
    const float* bnm    = (const float*)d_in[27];
    const float* bnv    = (const float*)d_in[28];
    const float* Kappa  = (const float*)d_in[29];
    const float* KcloseW = (const float*)d_in[30];
    const float* Kcloseb = (const float*)d_in[31];

    const int* row = EI;
    const int* col = EI + N_EDGES;

    char* ws = (char*)d_ws;
    size_t off = 0;
    auto alloc = [&](size_t bytes) -> void* {
        void* p = ws + off;
        off += (bytes + 255) & ~(size_t)255;
        return p;
    };

    float* B[10];
    for (int i = 0; i < 10; i++) B[i] = (float*)alloc((size_t)NB * 4);
    int*   ecol   = (int*)alloc((size_t)N_EDGES * 4);
    float* ewt    = (float*)alloc((size_t)N_EDGES * 4);
    int*   rowptr = (int*)alloc((size_t)(N_NODES + 1) * 4);
    int*   cursor = (int*)alloc((size_t)N_NODES * 4);
    int*   deg    = (int*)alloc((size_t)N_NODES * 4);
    float* dinv   = (float*)alloc((size_t)N_NODES * 4);
    int*   blksum = (int*)alloc(256 * 4);
    int*   blkoff = (int*)alloc(256 * 4);
    float* Mmat   = (float*)alloc(128 * 128 * 4);
    float* uvec   = (float*)alloc(512);
    float* vvec   = (float*)alloc(512);
    float* c0s    = (float*)alloc(256);
    float* Cm     = (float*)alloc(256);
    float* cvec   = (float*)alloc(256);
    float* scal   = (float*)alloc(256);
    int*   doneA  = (int*)alloc(256);

    float* TH = B[0];
    float* Z  = B[1];
    float* XB[4] = {B[2], B[3], B[4], B[5]};
    float* G[4]  = {B[6], B[7], B[8], B[9]};
    float* M1 = G[0], *M2 = G[1], *T1 = G[3];
    float* LPb = G[1];   /* aliases M2: M2 consumed in combine before LP writes */
    float* Pb  = G[2];
    float* Rb  = G[3];   /* aliases T1: combine writes R in-place over T1 */

    /* cooperative grid size: guarantee co-residency */
    int occ = 0;
    (void)hipOccupancyMaxActiveBlocksPerMultiprocessor(&occ, k_cg, 256, 0);
    if (occ < 1) occ = 1;
    int cgBlocks = occ * 256;
    if (cgBlocks > 2048) cgBlocks = 2048;

    /* CSR build */
    k_zero_i32<<<196, 256, 0, stream>>>(deg, N_NODES);
    k_count<<<(N_EDGES + 255) / 256, 256, 0, stream>>>(row, col, deg);
    k_scan1<<<SCAN_BLOCKS, 256, 0, stream>>>(deg, rowptr, blksum);
    k_scan2<<<1, 256, 0, stream>>>(blksum, blkoff);
    k_scan3<<<SCAN_BLOCKS, 256, 0, stream>>>(deg, blkoff, rowptr, dinv, cursor);
    k_scatter<<<(N_EDGES + 255) / 256, 256, 0, stream>>>(row, col, dinv, cursor, ecol, ewt);

    /* attention precompute */
    k_mmat<<<128, 128, 0, stream>>>(Wq, Wk, Mmat);
    k_uv<<<1, 128, 0, stream>>>(Wq, Wk, bq, bk, uvec, vvec, c0s);

    const int GEMM_GRID = (N_NODES + 63) / 64;

    /* opening */
    k_gemm128<<<GEMM_GRID, 256, 0, stream>>>(T, KopenW, Kopenb, TH, N_NODES, 1, 0, bnOg, bnOb, bnOm, bnOv);
    k_gemm128<<<GEMM_GRID, 256, 0, stream>>>(TH, convW, convb, Z, N_NODES, 2, 0, bnAg, bnAb, bnAm, bnAv);

    const float* hist[4] = {Z, Z, Z, Z};

    for (int jj = 0; jj < NLAYERS; jj++) {
        /* unique history slots */
        const float* uq[4];
        int nu = 0, gi[4];
        for (int i = 0; i < 4; i++) {
            int f = -1;
            for (int k = 0; k < nu; k++) if (uq[k] == hist[i]) f = k;
            if (f < 0) { uq[nu] = hist[i]; f = nu; nu++; }
            gi[i] = f;
        }
        for (int u = 0; u < nu; u++)
            k_gemm128<<<GEMM_GRID, 256, 0, stream>>>(uq[u], Mmat, nullptr, G[u], N_NODES, 0, 0,
                                                     nullptr, nullptr, nullptr, nullptr);
        k_zero16<<<1, 64, 0, stream>>>(Cm);
        k_attn<<<ATTN_BLOCKS, 256, 0, stream>>>(hist[0], hist[1], hist[2], hist[3],
                                                G[gi[0]], G[gi[1]], G[gi[2]], G[gi[3]],
                                                uvec, vvec, c0s, mha, Cm);
        k_cvec<<<1, 64, 0, stream>>>(Cm, cvec);
        k_t1<<<EW_BLOCKS, 256, 0, stream>>>(hist[0], hist[1], hist[2], hist[3], cvec, T1);

        k_gemm128<<<GEMM_GRID, 256, 0, stream>>>(T1, KR1W + (size_t)jj * 16384, KR1b + jj * 128, M1,
                                                 N_NODES, 0, 0, nullptr, nullptr, nullptr, nullptr);
        k_gemm128<<<GEMM_GRID, 256, 0, stream>>>(TH, KRU0W + (size_t)jj * 16384, KRU0b + jj * 128, M1,
                                                 N_NODES, 0, 1, nullptr, nullptr, nullptr, nullptr);
        k_gemm128<<<GEMM_GRID, 256, 0, stream>>>(T1, KR2W + (size_t)jj * 16384, KR2b + jj * 128, M2,
                                                 N_NODES, 0, 0, nullptr, nullptr, nullptr, nullptr);

        hipMemsetAsync(scal, 0, 128, stream);
        const float* bgj  = bng  + jj * 128;
        const float* bbj  = bnbb + jj * 128;
        const float* bmj  = bnm  + jj * 128;
        const float* bvj  = bnv  + jj * 128;
        const float* kapj = Kappa + jj * 128;
        float* Xj = XB[jj];
        const float* T1c = T1; const float* M1c = M1; const float* M2c = M2;
        void* cgArgs[] = {
            (void*)&T1c, (void*)&M1c, (void*)&M2c,
            (void*)&bgj, (void*)&bbj, (void*)&bmj, (void*)&bvj,
            (void*)&kapj,
            (void*)&rowptr, (void*)&ecol, (void*)&ewt,
            (void*)&Pb, (void*)&Xj, (void*)&Rb, (void*)&LPb,
            (void*)&scal
        };
        hipError_t ce = hipLaunchCooperativeKernel((const void*)k_cg, dim3(cgBlocks), dim3(256),
                                                   cgArgs, 0, stream);
        if (ce != hipSuccess) {
            /* fallback: same math, separate kernels */
            f_combine<<<EW_BLOCKS, 256, 0, stream>>>(T1c, M1c, M2c, bgj, bbj, bmj, bvj,
                                                     Pb, Xj, Rb, scal, doneA);
            for (int it = 0; it < CG_ITERS; it++) {
                f_spmv<<<SPMV_BLOCKS, 256, 0, stream>>>(rowptr, ecol, ewt, Pb, kapj, LPb, scal, doneA, it);
                f_xr<<<EW_BLOCKS, 256, 0, stream>>>(Xj, Pb, LPb, Rb, scal, doneA, it);
                f_pupd<<<EW_BLOCKS, 256, 0, stream>>>(Rb, Pb, scal, doneA, it);
            }
        }

        hist[0] = hist[1]; hist[1] = hist[2]; hist[2] = hist[3]; hist[3] = XB[jj];
    }

    k_close<<<(N_NODES + 255) / 256, 256, 0, stream>>>(XB[3], KcloseW, Kcloseb, (float*)d_out);
}

// Round 9
// 4849.531 us; speedup vs baseline: 2.3644x; 2.3644x over previous
//
#include <hip/hip_runtime.h>
#include <math.h>

#define N_NODES 50000
#define N_EDGES 800000
#define NHID    128
#define NOUT    40
#define NLAYERS 4
#define CG_ITERS 10
#define HSTEP   0.1f
#define EPS_BN  1e-5f

#define NB   (N_NODES * NHID)     /* 6,400,000 floats */
#define NB4  (NB / 4)             /* 1,600,000 float4 */

#define EW_BLOCKS   2048
#define SPMV_BLOCKS 2048
#define ATTN_BLOCKS 2048
#define SCAN_BLOCKS 196           /* ceil(50000/256) */

/* scalar slot layout (floats): all dots computed DIRECTLY each iteration */
#define SLOT_RR    0   /* dotRR[10]   (direct from R) */
#define SLOT_PLP   10  /* dotPLP[10]  */
#define SLOT_RLP   20  /* dotRLP[10]  */
#define SLOT_LPLP  30  /* dotLPLP[10] */

__device__ __forceinline__ float wred64(float v) {
    v += __shfl_xor(v, 32, 64);
    v += __shfl_xor(v, 16, 64);
    v += __shfl_xor(v, 8, 64);
    v += __shfl_xor(v, 4, 64);
    v += __shfl_xor(v, 2, 64);
    v += __shfl_xor(v, 1, 64);
    return v;
}

__device__ __forceinline__ int wscan64(int v, int lane) {
    int incl = v;
    #pragma unroll
    for (int off = 1; off < 64; off <<= 1) {
        int t = __shfl_up(incl, off, 64);
        if (lane >= off) incl += t;
    }
    return incl;
}

/* ---------------- CSR build ---------------- */

__global__ void k_zero_i32(int* p, int n) {
    int i = blockIdx.x * blockDim.x + threadIdx.x;
    int stride = gridDim.x * blockDim.x;
    for (; i < n; i += stride) p[i] = 0;
}

__global__ void k_count(const int* __restrict__ row, const int* __restrict__ col, int* __restrict__ deg) {
    int e = blockIdx.x * 256 + threadIdx.x;
    if (e < N_EDGES) {
        int r = row[e], c = col[e];
        if (r != c) atomicAdd(&deg[r], 1);
    }
}

__global__ __launch_bounds__(256) void k_scan1(const int* __restrict__ deg,
                                               int* __restrict__ rowptr, int* __restrict__ blksum) {
    __shared__ int wsum[4];
    int tid = threadIdx.x, lane = tid & 63, wid = tid >> 6;
    int i = blockIdx.x * 256 + tid;
    int v = (i < N_NODES) ? deg[i] : 0;
    int incl = wscan64(v, lane);
    if (lane == 63) wsum[wid] = incl;
    __syncthreads();
    int wpre = 0;
    for (int w = 0; w < wid; w++) wpre += wsum[w];
    incl += wpre;
    if (i < N_NODES) rowptr[i + 1] = incl;
    if (tid == 255) blksum[blockIdx.x] = incl;
}

__global__ __launch_bounds__(256) void k_scan2(const int* __restrict__ blksum, int* __restrict__ blkoff) {
    __shared__ int wsum[4];
    int tid = threadIdx.x, lane = tid & 63, wid = tid >> 6;
    int v = (tid < SCAN_BLOCKS) ? blksum[tid] : 0;
    int incl = wscan64(v, lane);
    if (lane == 63) wsum[wid] = incl;
    __syncthreads();
    int wpre = 0;
    for (int w = 0; w < wid; w++) wpre += wsum[w];
    incl += wpre;
    if (tid < SCAN_BLOCKS) blkoff[tid] = incl - v;
}

__global__ __launch_bounds__(256) void k_scan3(const int* __restrict__ deg, const int* __restrict__ blkoff,
                                               int* __restrict__ rowptr, float* __restrict__ dinv,
                                               int* __restrict__ cursor) {
    int i = blockIdx.x * 256 + threadIdx.x;
    if (i == 0) rowptr[0] = 0;
    if (i < N_NODES) {
        int incl = rowptr[i + 1] + blkoff[blockIdx.x];
        rowptr[i + 1] = incl;
        int d = deg[i];
        cursor[i] = incl - d;
        dinv[i] = (d > 0) ? rsqrtf((float)d) : 0.0f;
    }
}

__global__ void k_scatter(const int* __restrict__ row, const int* __restrict__ col,
                          const float* __restrict__ dinv, int* __restrict__ cursor,
                          int* __restrict__ ecol, float* __restrict__ ew) {
    int e = blockIdx.x * 256 + threadIdx.x;
    if (e < N_EDGES) {
        int r = row[e], c = col[e];
        if (r != c) {
            int p = atomicAdd(&cursor[r], 1);
            ecol[p] = c;
            ew[p] = -dinv[r] * dinv[c];
        }
    }
}

/* ---------------- attention precompute ---------------- */

__global__ void k_mmat(const float* __restrict__ Wq, const float* __restrict__ Wk, float* __restrict__ M) {
    int h1 = blockIdx.x, h2 = threadIdx.x;
    float s = 0.f;
    for (int d = 0; d < 128; ++d) s += Wq[d * 128 + h1] * Wk[d * 128 + h2];
    M[h1 * 128 + h2] = s;
}

__global__ void k_uv(const float* __restrict__ Wq, const float* __restrict__ Wk,
                     const float* __restrict__ bq, const float* __restrict__ bk,
                     float* __restrict__ u, float* __restrict__ v, float* __restrict__ c0) {
    int h = threadIdx.x;
    float su = 0.f, sv = 0.f;
    for (int d = 0; d < 128; ++d) {
        su += Wk[d * 128 + h] * bq[d];
        sv += Wq[d * 128 + h] * bk[d];
    }
    u[h] = su; v[h] = sv;
    if (h == 0) {
        float s = 0.f;
        for (int d = 0; d < 128; ++d) s += bq[d] * bk[d];
        *c0 = s;
    }
}

/* ---------------- GEMM ---------------- */

__global__ __launch_bounds__(256) void k_gemm128(
    const float* __restrict__ A, const float* __restrict__ W, const float* __restrict__ bias,
    float* __restrict__ C, int M, int epi, int accflag,
    const float* __restrict__ bng, const float* __restrict__ bnb,
    const float* __restrict__ bnm, const float* __restrict__ bnv)
{
    __shared__ float Wt[128][132];
    int tid = threadIdx.x;
    for (int i = tid; i < 128 * 128; i += 256) {
        int c = i >> 7, k = i & 127;
        Wt[k][c] = W[i];
    }
    __syncthreads();

    int tx = tid & 15, ty = tid >> 4;
    int r0 = blockIdx.x * 64 + ty * 4;
    int c0 = tx * 8;
    if (r0 >= M) return;

    float acc[4][8];
    #pragma unroll
    for (int i = 0; i < 4; i++)
        #pragma unroll
        for (int j = 0; j < 8; j++) acc[i][j] = 0.f;

    for (int k = 0; k < 128; k += 4) {
        float4 av[4];
        #pragma unroll
        for (int rr = 0; rr < 4; ++rr)
            av[rr] = *(const float4*)(A + (size_t)(r0 + rr) * 128 + k);
        #pragma unroll
        for (int kk = 0; kk < 4; ++kk) {
            float4 w0 = *(const float4*)&Wt[k + kk][c0];
            float4 w1 = *(const float4*)&Wt[k + kk][c0 + 4];
            #pragma unroll
            for (int rr = 0; rr < 4; ++rr) {
                float a = (kk == 0) ? av[rr].x : (kk == 1) ? av[rr].y : (kk == 2) ? av[rr].z : av[rr].w;
                acc[rr][0] += a * w0.x; acc[rr][1] += a * w0.y;
                acc[rr][2] += a * w0.z; acc[rr][3] += a * w0.w;
                acc[rr][4] += a * w1.x; acc[rr][5] += a * w1.y;
                acc[rr][6] += a * w1.z; acc[rr][7] += a * w1.w;
            }
        }
    }

    #pragma unroll
    for (int rr = 0; rr < 4; ++rr) {
        int r = r0 + rr;
        float out[8];
        #pragma unroll
        for (int j = 0; j < 8; j++) {
            int c = c0 + j;
            float x = acc[rr][j];
            if (bias) x += bias[c];
            if (accflag) x += C[(size_t)r * 128 + c];
            if (epi) {
                float xb = (x - bnm[c]) * rsqrtf(bnv[c] + EPS_BN) * bng[c] + bnb[c];
                x = (epi == 1) ? (xb > 0.f ? xb : expm1f(xb)) : (xb > 0.f ? xb : 0.f);
            }
            out[j] = x;
        }
        *(float4*)(C + (size_t)r * 128 + c0)     = make_float4(out[0], out[1], out[2], out[3]);
        *(float4*)(C + (size_t)r * 128 + c0 + 4) = make_float4(out[4], out[5], out[6], out[7]);
    }
}

/* ---------------- Kclose ---------------- */

__global__ __launch_bounds__(256) void k_close(const float* __restrict__ A, const float* __restrict__ W,
                                               const float* __restrict__ bias, float* __restrict__ out) {
    __shared__ float Wl[40 * 128];
    int tid = threadIdx.x;
    for (int i = tid; i < 40 * 128; i += 256) Wl[i] = W[i];
    __syncthreads();
    int n = blockIdx.x * 256 + tid;
    if (n >= N_NODES) return;
    float acc[40];
    #pragma unroll
    for (int c = 0; c < 40; c++) acc[c] = bias[c];
    for (int k = 0; k < 128; k += 4) {
        float4 a = *(const float4*)(A + (size_t)n * 128 + k);
        #pragma unroll
        for (int c = 0; c < 40; c++) {
            float4 w = *(const float4*)&Wl[c * 128 + k];
            acc[c] += a.x * w.x + a.y * w.y + a.z * w.z + a.w * w.w;
        }
    }
    #pragma unroll
    for (int c = 0; c < 40; c++) out[(size_t)n * 40 + c] = acc[c];
}

/* ---------------- attention ---------------- */

__global__ void k_zero16(float* p) {
    if (threadIdx.x < 16) p[threadIdx.x] = 0.f;
}

__global__ __launch_bounds__(256) void k_attn(
    const float* __restrict__ h0, const float* __restrict__ h1,
    const float* __restrict__ h2, const float* __restrict__ h3,
    const float* __restrict__ g0, const float* __restrict__ g1,
    const float* __restrict__ g2, const float* __restrict__ g3,
    const float* __restrict__ u, const float* __restrict__ v,
    const float* __restrict__ c0p, const float* __restrict__ mha,
    float* __restrict__ Cm)
{
    int tid = threadIdx.x;
    int lane = tid & 63, wid = tid >> 6;
    const float* hp[4] = {h0, h1, h2, h3};
    const float* gp[4] = {g0, g1, g2, g3};
    float uu0 = u[lane], uu1 = u[lane + 64];
    float vv0 = v[lane], vv1 = v[lane + 64];
    float c0v = *c0p;
    float rf = mha[0]; rf = rf > 0.f ? rf : 0.f;
    const float scale = 0.08838834764831845f; /* 128^-0.5 */

    float tacc = 0.f;    /* meaningful in lanes 0..15 */
    int totalWaves = gridDim.x * 4;
    for (int n = blockIdx.x * 4 + wid; n < N_NODES; n += totalWaves) {
        float a0[4], a1[4], gg0[4], gg1[4];
        size_t base = (size_t)n * 128 + lane;
        #pragma unroll
        for (int o = 0; o < 4; o++) {
            a0[o] = hp[o][base];  a1[o] = hp[o][base + 64];
            gg0[o] = gp[o][base]; gg1[o] = gp[o][base + 64];
        }
        float s[4][4], pu[4], pv[4];
        #pragma unroll
        for (int i = 0; i < 4; i++) {
            pu[i] = wred64(uu0 * a0[i] + uu1 * a1[i]);
            pv[i] = wred64(vv0 * a0[i] + vv1 * a1[i]);
            #pragma unroll
            for (int j = 0; j < 4; j++)
                s[i][j] = wred64(a0[i] * gg0[j] + a1[i] * gg1[j]);
        }
        #pragma unroll
        for (int i = 0; i < 4; i++)
            #pragma unroll
            for (int j = 0; j < 4; j++)
                s[i][j] = scale * (s[i][j] + pu[j] + pv[i] + c0v);

        if (lane < 16) {
            int i = lane >> 2, j = lane & 3;
            float m = fmaxf(fmaxf(s[i][0], s[i][1]), fmaxf(s[i][2], s[i][3]));
            float den = expf(s[i][0] - m) + expf(s[i][1] - m) + expf(s[i][2] - m) + expf(s[i][3] - m);
            float attn = expf(s[i][j] - m) / den;
            tacc += logf(attn * rf + 1e-4f);
        }
    }
    __shared__ float accum[4][16];
    if (lane < 16) accum[wid][lane] = tacc;
    __syncthreads();
    if (tid < 16)
        atomicAdd(&Cm[tid], accum[0][tid] + accum[1][tid] + accum[2][tid] + accum[3][tid]);
}

__global__ void k_cvec(const float* __restrict__ Cm, float* __restrict__ c) {
    if (threadIdx.x == 0) {
        float cm[16];
        for (int i = 0; i < 16; i++) cm[i] = Cm[i] / (float)N_NODES;
        float cc[4];
        for (int j = 0; j < 4; j++) cc[j] = 0.5f * (cm[12 + j] + cm[j * 4 + 3]);
        float s = cc[0] + cc[1] + cc[2] + cc[3];
        for (int j = 0; j < 4; j++) c[j] = cc[j] / s;
    }
}

__global__ __launch_bounds__(256) void k_t1(
    const float* __restrict__ h0, const float* __restrict__ h1,
    const float* __restrict__ h2, const float* __restrict__ h3,
    const float* __restrict__ c, float* __restrict__ T1)
{
    float c0 = c[0], c1 = c[1], c2 = c[2], c3 = c[3];
    int stride = gridDim.x * blockDim.x;
    for (int i = blockIdx.x * blockDim.x + threadIdx.x; i < NB4; i += stride) {
        float4 x0 = ((const float4*)h0)[i];
        float4 x1 = ((const float4*)h1)[i];
        float4 x2 = ((const float4*)h2)[i];
        float4 x3 = ((const float4*)h3)[i];
        float4 o;
        o.x = c0 * x0.x + c1 * x1.x + c2 * x2.x + c3 * x3.x;
        o.y = c0 * x0.y + c1 * x1.y + c2 * x2.y + c3 * x3.y;
        o.z = c0 * x0.z + c1 * x1.z + c2 * x2.z + c3 * x3.z;
        o.w = c0 * x0.w + c1 * x1.w + c2 * x2.w + c3 * x3.w;
        ((float4*)T1)[i] = o;
    }
}

/* ---------------- combine + CG init (fused): Tr = elu(bn(T1 + h*dT)); P=X=R=Tr ----------------
   Rv may alias T1v (element-wise in-place). */

__global__ __launch_bounds__(256) void k_combine(
    const float* T1v, const float* __restrict__ M1v, const float* __restrict__ M2v,
    const float* __restrict__ g, const float* __restrict__ b,
    const float* __restrict__ m, const float* __restrict__ v,
    float* __restrict__ Pv, float* __restrict__ Xv, float* Rv,
    float* __restrict__ scal, int* __restrict__ doneArr)
{
    if (blockIdx.x == 0) {
        if (threadIdx.x < 40) scal[threadIdx.x] = 0.f;
        if (threadIdx.x == 40) doneArr[0] = 0;
    }
    int stride = gridDim.x * blockDim.x;
    for (int i = blockIdx.x * blockDim.x + threadIdx.x; i < NB4; i += stride) {
        float4 t1 = ((const float4*)T1v)[i];
        float4 m1 = ((const float4*)M1v)[i];
        float4 m2 = ((const float4*)M2v)[i];
        int chb = (i * 4) & 127;
        float tt[4] = {t1.x, t1.y, t1.z, t1.w};
        float a1[4] = {m1.x, m1.y, m1.z, m1.w};
        float a2[4] = {m2.x, m2.y, m2.z, m2.w};
        float o[4];
        #pragma unroll
        for (int k = 0; k < 4; k++) {
            float cl = fminf(fmaxf(a2[k], -1.f), 1.f);
            float x = tt[k] + HSTEP * (a1[k] + tt[k] * cl);
            int ch = chb + k;
            float xb = (x - m[ch]) * rsqrtf(v[ch] + EPS_BN) * g[ch] + b[ch];
            o[k] = xb > 0.f ? xb : expm1f(xb);
        }
        float4 o4 = make_float4(o[0], o[1], o[2], o[3]);
        ((float4*)Pv)[i] = o4;
        ((float4*)Xv)[i] = o4;
        ((float4*)Rv)[i] = o4;
    }
}

/* ---------------- CG kernels ---------------- */

/* SpMV + LP + 4 DIRECT dots (RR from current R — no cross-iteration carry).
   Wave-per-row, float2 lanes, 8-unrolled edge loop. Early-exit once converged. */
__global__ __launch_bounds__(256) void k_spmv_lp(
    const int* __restrict__ rowptr, const int* __restrict__ ecol, const float* __restrict__ ewt,
    const float* __restrict__ P, const float* __restrict__ R, const float* __restrict__ Kap,
    float* __restrict__ LP, float* __restrict__ scal, const int* __restrict__ doneArr, int it)
{
    if (doneArr[it]) return;
    int tid = threadIdx.x;
    int lane = tid & 63, wid = tid >> 6;
    float2 kd2 = ((const float2*)Kap)[lane];
    kd2.x = fminf(fmaxf(kd2.x, 0.f), 1.f);
    kd2.y = fminf(fmaxf(kd2.y, 0.f), 1.f);
    const float2* P2 = (const float2*)P;
    const float2* R2 = (const float2*)R;
    float2* LP2 = (float2*)LP;

    float pPLP = 0.f, pRR = 0.f, pRLP = 0.f, pLPLP = 0.f;
    int totalWaves = gridDim.x * 4;
    for (int r = blockIdx.x * 4 + wid; r < N_NODES; r += totalWaves) {
        int e0 = rowptr[r], e1 = rowptr[r + 1];
        float ax = 0.f, ay = 0.f;
        int e = e0;
        for (; e + 8 <= e1; e += 8) {
            int   c0 = ecol[e],     c1 = ecol[e + 1], c2 = ecol[e + 2], c3 = ecol[e + 3];
            int   c4 = ecol[e + 4], c5 = ecol[e + 5], c6 = ecol[e + 6], c7 = ecol[e + 7];
            float w0 = ewt[e],     w1 = ewt[e + 1], w2 = ewt[e + 2], w3 = ewt[e + 3];
            float w4 = ewt[e + 4], w5 = ewt[e + 5], w6 = ewt[e + 6], w7 = ewt[e + 7];
            float2 p0 = P2[(size_t)c0 * 64 + lane];
            float2 p1 = P2[(size_t)c1 * 64 + lane];
            float2 p2 = P2[(size_t)c2 * 64 + lane];
            float2 p3 = P2[(size_t)c3 * 64 + lane];
            float2 p4 = P2[(size_t)c4 * 64 + lane];
            float2 p5 = P2[(size_t)c5 * 64 + lane];
            float2 p6 = P2[(size_t)c6 * 64 + lane];
            float2 p7 = P2[(size_t)c7 * 64 + lane];
            ax += w0 * p0.x + w1 * p1.x + w2 * p2.x + w3 * p3.x
                + w4 * p4.x + w5 * p5.x + w6 * p6.x + w7 * p7.x;
            ay += w0 * p0.y + w1 * p1.y + w2 * p2.y + w3 * p3.y
                + w4 * p4.y + w5 * p5.y + w6 * p6.y + w7 * p7.y;
        }
        for (; e < e1; ++e) {
            int c = ecol[e]; float w = ewt[e];
            float2 p = P2[(size_t)c * 64 + lane];
            ax += w * p.x; ay += w * p.y;
        }
        size_t idx = (size_t)r * 64 + lane;
        float2 pv = P2[idx];
        float2 rv = R2[idx];
        float2 lp;
        lp.x = pv.x + HSTEP * (kd2.x * (pv.x + ax));
        lp.y = pv.y + HSTEP * (kd2.y * (pv.y + ay));
        LP2[idx] = lp;
        pPLP  += pv.x * lp.x + pv.y * lp.y;
        pRR   += rv.x * rv.x + rv.y * rv.y;
        pRLP  += rv.x * lp.x + rv.y * lp.y;
        pLPLP += lp.x * lp.x + lp.y * lp.y;
    }
    pPLP = wred64(pPLP); pRR = wred64(pRR); pRLP = wred64(pRLP); pLPLP = wred64(pLPLP);
    __shared__ float red[16];
    if (lane == 0) { red[wid] = pPLP; red[4 + wid] = pRR; red[8 + wid] = pRLP; red[12 + wid] = pLPLP; }
    __syncthreads();
    if (tid == 0) {
        atomicAdd(&scal[SLOT_PLP  + it], red[0] + red[1] + red[2] + red[3]);
        atomicAdd(&scal[SLOT_RR   + it], red[4] + red[5] + red[6] + red[7]);
        atomicAdd(&scal[SLOT_RLP  + it], red[8] + red[9] + red[10] + red[11]);
        atomicAdd(&scal[SLOT_LPLP + it], red[12] + red[13] + red[14] + red[15]);
    }
}

/* Fused X/R/P update (validated in round 5: absmax identical to 3-kernel version).
   nr computed algebraically WITHIN the iteration only; next iteration's RR is
   recomputed directly from R in k_spmv_lp, so no error carry-over. */
__global__ __launch_bounds__(256) void k_upd(
    float* __restrict__ X, float* __restrict__ P, const float* __restrict__ LP,
    float* __restrict__ R, const float* __restrict__ scal, int* __restrict__ doneArr, int it)
{
    int d = doneArr[it];
    float RR   = scal[SLOT_RR + it];
    float PLP  = scal[SLOT_PLP + it];
    float RLP  = scal[SLOT_RLP + it];
    float LPLP = scal[SLOT_LPLP + it];
    float alpha = RR / (PLP + 1e-6f);
    float nr = RR - 2.f * alpha * RLP + alpha * alpha * LPLP;
    int d2 = d || (nr < 1e-5f);
    if (blockIdx.x == 0 && threadIdx.x == 0) doneArr[it + 1] = d2;
    if (d) return;
    float beta = nr / (RR + 1e-6f);
    int stride = gridDim.x * blockDim.x;
    for (int i = blockIdx.x * blockDim.x + threadIdx.x; i < NB4; i += stride) {
        float4 x = ((const float4*)X)[i];
        float4 p = ((const float4*)P)[i];
        float4 lp = ((const float4*)LP)[i];
        float4 r = ((const float4*)R)[i];
        x.x += alpha * p.x; x.y += alpha * p.y; x.z += alpha * p.z; x.w += alpha * p.w;
        r.x -= alpha * lp.x; r.y -= alpha * lp.y; r.z -= alpha * lp.z; r.w -= alpha * lp.w;
        ((float4*)X)[i] = x;
        ((float4*)R)[i] = r;
        if (!d2) {
            p.x = r.x + beta * p.x; p.y = r.y + beta * p.y;
            p.z = r.z + beta * p.z; p.w = r.w + beta * p.w;
            ((float4*)P)[i] = p;
        }
    }
}

/* ---------------- host ---------------- */

extern "C" void kernel_launch(void* const* d_in, const int* in_sizes, int n_in,
                              void* d_out, int out_size, void* d_ws, size_t ws_size,
                              hipStream_t stream) {
    (void)in_sizes; (void)n_in; (void)out_size; (void)ws_size;

    const float* T      = (const float*)d_in[0];
    const int*   EI     = (const int*)d_in[1];
    const float* KopenW = (const float*)d_in[2];
    const float* Kopenb = (const float*)d_in[3];
    const float* bnOg   = (const float*)d_in[4];
    const float* bnOb   = (const float*)d_in[5];
    const float* bnOm   = (const float*)d_in[6];
    const float* bnOv   = (const float*)d_in[7];
    const float* convW  = (const float*)d_in[8];
    const float* convb  = (const float*)d_in[9];
    const float* bnAg   = (const float*)d_in[10];
    const float* bnAb   = (const float*)d_in[11];
    const float* bnAm   = (const float*)d_in[12];
    const float* bnAv   = (const float*)d_in[13];
    const float* Wq     = (const float*)d_in[14];
    const float* bq     = (const float*)d_in[15];
    const float* Wk     = (const float*)d_in[16];
    const float* bk     = (const float*)d_in[17];
    const float* mha    = (const float*)d_in[18];
    const float* KR1W   = (const float*)d_in[19];
    const float* KR1b   = (const float*)d_in[20];
    const float* KR2W   = (const float*)d_in[21];
    const float* KR2b   = (const float*)d_in[22];
    const float* KRU0W  = (const float*)d_in[23];
    const float* KRU0b  = (const float*)d_in[24];
    const float* bng    = (const float*)d_in[25];
    const float* bnbb   = (const float*)d_in[26];
    const float* bnm    = (const float*)d_in[27];
    const float* bnv    = (const float*)d_in[28];
    const float* Kappa  = (const float*)d_in[29];
    const float* KcloseW = (const float*)d_in[30];
    const float* Kcloseb = (const float*)d_in[31];

    const int* row = EI;
    const int* col = EI + N_EDGES;

    char* ws = (char*)d_ws;
    size_t off = 0;
    auto alloc = [&](size_t bytes) -> void* {
        void* p = ws + off;
        off += (bytes + 255) & ~(size_t)255;
        return p;
    };

    float* B[10];
    for (int i = 0; i < 10; i++) B[i] = (float*)alloc((size_t)NB * 4);
    int*   ecol   = (int*)alloc((size_t)N_EDGES * 4);
    float* ewt    = (float*)alloc((size_t)N_EDGES * 4);
    int*   rowptr = (int*)alloc((size_t)(N_NODES + 1) * 4);
    int*   cursor = (int*)alloc((size_t)N_NODES * 4);
    int*   deg    = (int*)alloc((size_t)N_NODES * 4);
    float* dinv   = (float*)alloc((size_t)N_NODES * 4);
    int*   blksum = (int*)alloc(256 * 4);
    int*   blkoff = (int*)alloc(256 * 4);
    float* Mmat   = (float*)alloc(128 * 128 * 4);
    float* uvec   = (float*)alloc(512);
    float* vvec   = (float*)alloc(512);
    float* c0s    = (float*)alloc(256);
    float* Cm     = (float*)alloc(256);
    float* cvec   = (float*)alloc(256);
    float* scal   = (float*)alloc(256);
    int*   doneA  = (int*)alloc(256);

    float* TH = B[0];
    float* Z  = B[1];
    float* XB[4] = {B[2], B[3], B[4], B[5]};
    float* G[4]  = {B[6], B[7], B[8], B[9]};
    float* M1 = G[0], *M2 = G[1], *T1 = G[3];
    float* LPb = G[1];   /* aliases M2: M2 consumed in combine before LP writes */
    float* Pb  = G[2];
    float* Rb  = G[3];   /* aliases T1: combine writes R in-place over T1 */

    /* CSR build */
    k_zero_i32<<<196, 256, 0, stream>>>(deg, N_NODES);
    k_count<<<(N_EDGES + 255) / 256, 256, 0, stream>>>(row, col, deg);
    k_scan1<<<SCAN_BLOCKS, 256, 0, stream>>>(deg, rowptr, blksum);
    k_scan2<<<1, 256, 0, stream>>>(blksum, blkoff);
    k_scan3<<<SCAN_BLOCKS, 256, 0, stream>>>(deg, blkoff, rowptr, dinv, cursor);
    k_scatter<<<(N_EDGES + 255) / 256, 256, 0, stream>>>(row, col, dinv, cursor, ecol, ewt);

    /* attention precompute */
    k_mmat<<<128, 128, 0, stream>>>(Wq, Wk, Mmat);
    k_uv<<<1, 128, 0, stream>>>(Wq, Wk, bq, bk, uvec, vvec, c0s);

    const int GEMM_GRID = (N_NODES + 63) / 64;

    /* opening */
    k_gemm128<<<GEMM_GRID, 256, 0, stream>>>(T, KopenW, Kopenb, TH, N_NODES, 1, 0, bnOg, bnOb, bnOm, bnOv);
    k_gemm128<<<GEMM_GRID, 256, 0, stream>>>(TH, convW, convb, Z, N_NODES, 2, 0, bnAg, bnAb, bnAm, bnAv);

    const float* hist[4] = {Z, Z, Z, Z};

    for (int jj = 0; jj < NLAYERS; jj++) {
        /* unique history slots */
        const float* uq[4];
        int nu = 0, gi[4];
        for (int i = 0; i < 4; i++) {
            int f = -1;
            for (int k = 0; k < nu; k++) if (uq[k] == hist[i]) f = k;
            if (f < 0) { uq[nu] = hist[i]; f = nu; nu++; }
            gi[i] = f;
        }
        for (int u = 0; u < nu; u++)
            k_gemm128<<<GEMM_GRID, 256, 0, stream>>>(uq[u], Mmat, nullptr, G[u], N_NODES, 0, 0,
                                                     nullptr, nullptr, nullptr, nullptr);
        k_zero16<<<1, 64, 0, stream>>>(Cm);
        k_attn<<<ATTN_BLOCKS, 256, 0, stream>>>(hist[0], hist[1], hist[2], hist[3],
                                                G[gi[0]], G[gi[1]], G[gi[2]], G[gi[3]],
                                                uvec, vvec, c0s, mha, Cm);
        k_cvec<<<1, 64, 0, stream>>>(Cm, cvec);
        k_t1<<<EW_BLOCKS, 256, 0, stream>>>(hist[0], hist[1], hist[2], hist[3], cvec, T1);

        k_gemm128<<<GEMM_GRID, 256, 0, stream>>>(T1, KR1W + (size_t)jj * 16384, KR1b + jj * 128, M1,
                                                 N_NODES, 0, 0, nullptr, nullptr, nullptr, nullptr);
        k_gemm128<<<GEMM_GRID, 256, 0, stream>>>(TH, KRU0W + (size_t)jj * 16384, KRU0b + jj * 128, M1,
                                                 N_NODES, 0, 1, nullptr, nullptr, nullptr, nullptr);
        k_gemm128<<<GEMM_GRID, 256, 0, stream>>>(T1, KR2W + (size_t)jj * 16384, KR2b + jj * 128, M2,
                                                 N_NODES, 0, 0, nullptr, nullptr, nullptr, nullptr);
        /* combine + CG init: P = X = R = Tr (R written in-place over T1) */
        k_combine<<<EW_BLOCKS, 256, 0, stream>>>(T1, M1, M2,
                                                 bng + jj * 128, bnbb + jj * 128, bnm + jj * 128, bnv + jj * 128,
                                                 Pb, XB[jj], Rb, scal, doneA);

        for (int it = 0; it < CG_ITERS; it++) {
            k_spmv_lp<<<SPMV_BLOCKS, 256, 0, stream>>>(rowptr, ecol, ewt, Pb, Rb, Kappa + jj * 128,
                                                       LPb, scal, doneA, it);
            k_upd<<<EW_BLOCKS, 256, 0, stream>>>(XB[jj], Pb, LPb, Rb, scal, doneA, it);
        }

        hist[0] = hist[1]; hist[1] = hist[2]; hist[2] = hist[3]; hist[3] = XB[jj];
    }

    k_close<<<(N_NODES + 255) / 256, 256, 0, stream>>>(XB[3], KcloseW, Kcloseb, (float*)d_out);
}

// Round 12
// 4553.000 us; speedup vs baseline: 2.5184x; 1.0651x over previous
//
#include <hip/hip_runtime.h>
#include <math.h>

#define N_NODES 50000
#define N_EDGES 800000
#define NHID    128
#define NOUT    40
#define NLAYERS 4
#define CG_ITERS 10
#define HSTEP   0.1f
#define EPS_BN  1e-5f

#define NB   (N_NODES * NHID)     /* 6,400,000 floats */
#define NB4  (NB / 4)             /* 1,600,000 float4 */

#define EW_BLOCKS   2048
#define SPMV_BLOCKS 2048
#define ATTN_BLOCKS 2048
#define SCAN_BLOCKS 196           /* ceil(50000/256) */

/* scalar slot layout (floats): all dots computed DIRECTLY each iteration */
#define SLOT_RR    0   /* dotRR[10]   (direct from R) */
#define SLOT_PLP   10  /* dotPLP[10]  */
#define SLOT_RLP   20  /* dotRLP[10]  */
#define SLOT_LPLP  30  /* dotLPLP[10] */

__device__ __forceinline__ float wred64(float v) {
    v += __shfl_xor(v, 32, 64);
    v += __shfl_xor(v, 16, 64);
    v += __shfl_xor(v, 8, 64);
    v += __shfl_xor(v, 4, 64);
    v += __shfl_xor(v, 2, 64);
    v += __shfl_xor(v, 1, 64);
    return v;
}

__device__ __forceinline__ int wscan64(int v, int lane) {
    int incl = v;
    #pragma unroll
    for (int off = 1; off < 64; off <<= 1) {
        int t = __shfl_up(incl, off, 64);
        if (lane >= off) incl += t;
    }
    return incl;
}

/* bf16 pack (RNE) of two floats -> one uint (lo = a, hi = b) */
__device__ __forceinline__ unsigned bfpack2(float a, float b) {
    unsigned ua = __float_as_uint(a); ua += 0x7fffu + ((ua >> 16) & 1u);
    unsigned ub = __float_as_uint(b); ub += 0x7fffu + ((ub >> 16) & 1u);
    return (ua >> 16) | (ub & 0xffff0000u);
}

/* decode: x = bf16 in low half, y = bf16 in high half */
__device__ __forceinline__ float2 bfget2(unsigned v) {
    float2 r;
    r.x = __uint_as_float(v << 16);
    r.y = __uint_as_float(v & 0xffff0000u);
    return r;
}

/* ---------------- CSR build ---------------- */

__global__ void k_zero_i32(int* p, int n) {
    int i = blockIdx.x * blockDim.x + threadIdx.x;
    int stride = gridDim.x * blockDim.x;
    for (; i < n; i += stride) p[i] = 0;
}

__global__ void k_count(const int* __restrict__ row, const int* __restrict__ col, int* __restrict__ deg) {
    int e = blockIdx.x * 256 + threadIdx.x;
    if (e < N_EDGES) {
        int r = row[e], c = col[e];
        if (r != c) atomicAdd(&deg[r], 1);
    }
}

__global__ __launch_bounds__(256) void k_scan1(const int* __restrict__ deg,
                                               int* __restrict__ rowptr, int* __restrict__ blksum) {
    __shared__ int wsum[4];
    int tid = threadIdx.x, lane = tid & 63, wid = tid >> 6;
    int i = blockIdx.x * 256 + tid;
    int v = (i < N_NODES) ? deg[i] : 0;
    int incl = wscan64(v, lane);
    if (lane == 63) wsum[wid] = incl;
    __syncthreads();
    int wpre = 0;
    for (int w = 0; w < wid; w++) wpre += wsum[w];
    incl += wpre;
    if (i < N_NODES) rowptr[i + 1] = incl;
    if (tid == 255) blksum[blockIdx.x] = incl;
}

__global__ __launch_bounds__(256) void k_scan2(const int* __restrict__ blksum, int* __restrict__ blkoff) {
    __shared__ int wsum[4];
    int tid = threadIdx.x, lane = tid & 63, wid = tid >> 6;
    int v = (tid < SCAN_BLOCKS) ? blksum[tid] : 0;
    int incl = wscan64(v, lane);
    if (lane == 63) wsum[wid] = incl;
    __syncthreads();
    int wpre = 0;
    for (int w = 0; w < wid; w++) wpre += wsum[w];
    incl += wpre;
    if (tid < SCAN_BLOCKS) blkoff[tid] = incl - v;
}

__global__ __launch_bounds__(256) void k_scan3(const int* __restrict__ deg, const int* __restrict__ blkoff,
                                               int* __restrict__ rowptr, float* __restrict__ dinv,
                                               int* __restrict__ cursor) {
    int i = blockIdx.x * 256 + threadIdx.x;
    if (i == 0) rowptr[0] = 0;
    if (i < N_NODES) {
        int incl = rowptr[i + 1] + blkoff[blockIdx.x];
        rowptr[i + 1] = incl;
        int d = deg[i];
        cursor[i] = incl - d;
        dinv[i] = (d > 0) ? rsqrtf((float)d) : 0.0f;
    }
}

__global__ void k_scatter(const int* __restrict__ row, const int* __restrict__ col,
                          const float* __restrict__ dinv, int* __restrict__ cursor,
                          int* __restrict__ ecol, float* __restrict__ ew) {
    int e = blockIdx.x * 256 + threadIdx.x;
    if (e < N_EDGES) {
        int r = row[e], c = col[e];
        if (r != c) {
            int p = atomicAdd(&cursor[r], 1);
            ecol[p] = c;
            ew[p] = -dinv[r] * dinv[c];
        }
    }
}

/* ---------------- attention precompute ---------------- */

__global__ void k_mmat(const float* __restrict__ Wq, const float* __restrict__ Wk, float* __restrict__ M) {
    int h1 = blockIdx.x, h2 = threadIdx.x;
    float s = 0.f;
    for (int d = 0; d < 128; ++d) s += Wq[d * 128 + h1] * Wk[d * 128 + h2];
    M[h1 * 128 + h2] = s;
}

__global__ void k_uv(const float* __restrict__ Wq, const float* __restrict__ Wk,
                     const float* __restrict__ bq, const float* __restrict__ bk,
                     float* __restrict__ u, float* __restrict__ v, float* __restrict__ c0) {
    int h = threadIdx.x;
    float su = 0.f, sv = 0.f;
    for (int d = 0; d < 128; ++d) {
        su += Wk[d * 128 + h] * bq[d];
        sv += Wq[d * 128 + h] * bk[d];
    }
    u[h] = su; v[h] = sv;
    if (h == 0) {
        float s = 0.f;
        for (int d = 0; d < 128; ++d) s += bq[d] * bk[d];
        *c0 = s;
    }
}

/* ---------------- GEMM ---------------- */

__global__ __launch_bounds__(256) void k_gemm128(
    const float* __restrict__ A, const float* __restrict__ W, const float* __restrict__ bias,
    float* __restrict__ C, int M, int epi, int accflag,
    const float* __restrict__ bng, const float* __restrict__ bnb,
    const float* __restrict__ bnm, const float* __restrict__ bnv)
{
    __shared__ float Wt[128][132];
    int tid = threadIdx.x;
    for (int i = tid; i < 128 * 128; i += 256) {
        int c = i >> 7, k = i & 127;
        Wt[k][c] = W[i];
    }
    __syncthreads();

    int tx = tid & 15, ty = tid >> 4;
    int r0 = blockIdx.x * 64 + ty * 4;
    int c0 = tx * 8;
    if (r0 >= M) return;

    float acc[4][8];
    #pragma unroll
    for (int i = 0; i < 4; i++)
        #pragma unroll
        for (int j = 0; j < 8; j++) acc[i][j] = 0.f;

    for (int k = 0; k < 128; k += 4) {
        float4 av[4];
        #pragma unroll
        for (int rr = 0; rr < 4; ++rr)
            av[rr] = *(const float4*)(A + (size_t)(r0 + rr) * 128 + k);
        #pragma unroll
        for (int kk = 0; kk < 4; ++kk) {
            float4 w0 = *(const float4*)&Wt[k + kk][c0];
            float4 w1 = *(const float4*)&Wt[k + kk][c0 + 4];
            #pragma unroll
            for (int rr = 0; rr < 4; ++rr) {
                float a = (kk == 0) ? av[rr].x : (kk == 1) ? av[rr].y : (kk == 2) ? av[rr].z : av[rr].w;
                acc[rr][0] += a * w0.x; acc[rr][1] += a * w0.y;
                acc[rr][2] += a * w0.z; acc[rr][3] += a * w0.w;
                acc[rr][4] += a * w1.x; acc[rr][5] += a * w1.y;
                acc[rr][6] += a * w1.z; acc[rr][7] += a * w1.w;
            }
        }
    }

    #pragma unroll
    for (int rr = 0; rr < 4; ++rr) {
        int r = r0 + rr;
        float out[8];
        #pragma unroll
        for (int j = 0; j < 8; j++) {
            int c = c0 + j;
            float x = acc[rr][j];
            if (bias) x += bias[c];
            if (accflag) x += C[(size_t)r * 128 + c];
            if (epi) {
                float xb = (x - bnm[c]) * rsqrtf(bnv[c] + EPS_BN) * bng[c] + bnb[c];
                x = (epi == 1) ? (xb > 0.f ? xb : expm1f(xb)) : (xb > 0.f ? xb : 0.f);
            }
            out[j] = x;
        }
        *(float4*)(C + (size_t)r * 128 + c0)     = make_float4(out[0], out[1], out[2], out[3]);
        *(float4*)(C + (size_t)r * 128 + c0 + 4) = make_float4(out[4], out[5], out[6], out[7]);
    }
}

/* ---------------- Kclose ---------------- */

__global__ __launch_bounds__(256) void k_close(const float* __restrict__ A, const float* __restrict__ W,
                                               const float* __restrict__ bias, float* __restrict__ out) {
    __shared__ float Wl[40 * 128];
    int tid = threadIdx.x;
    for (int i = tid; i < 40 * 128; i += 256) Wl[i] = W[i];
    __syncthreads();
    int n = blockIdx.x * 256 + tid;
    if (n >= N_NODES) return;
    float acc[40];
    #pragma unroll
    for (int c = 0; c < 40; c++) acc[c] = bias[c];
    for (int k = 0; k < 128; k += 4) {
        float4 a = *(const float4*)(A + (size_t)n * 128 + k);
        #pragma unroll
        for (int c = 0; c < 40; c++) {
            float4 w = *(const float4*)&Wl[c * 128 + k];
            acc[c] += a.x * w.x + a.y * w.y + a.z * w.z + a.w * w.w;
        }
    }
    #pragma unroll
    for (int c = 0; c < 40; c++) out[(size_t)n * 40 + c] = acc[c];
}

/* ---------------- attention ---------------- */

__global__ void k_zero16(float* p) {
    if (threadIdx.x < 16) p[threadIdx.x] = 0.f;
}

__global__ __launch_bounds__(256) void k_attn(
    const float* __restrict__ h0, const float* __restrict__ h1,
    const float* __restrict__ h2, const float* __restrict__ h3,
    const float* __restrict__ g0, const float* __restrict__ g1,
    const float* __restrict__ g2, const float* __restrict__ g3,
    const float* __restrict__ u, const float* __restrict__ v,
    const float* __restrict__ c0p, const float* __restrict__ mha,
    float* __restrict__ Cm)
{
    int tid = threadIdx.x;
    int lane = tid & 63, wid = tid >> 6;
    const float* hp[4] = {h0, h1, h2, h3};
    const float* gp[4] = {g0, g1, g2, g3};
    float uu0 = u[lane], uu1 = u[lane + 64];
    float vv0 = v[lane], vv1 = v[lane + 64];
    float c0v = *c0p;
    float rf = mha[0]; rf = rf > 0.f ? rf : 0.f;
    const float scale = 0.08838834764831845f; /* 128^-0.5 */

    float tacc = 0.f;    /* meaningful in lanes 0..15 */
    int totalWaves = gridDim.x * 4;
    for (int n = blockIdx.x * 4 + wid; n < N_NODES; n += totalWaves) {
        float a0[4], a1[4], gg0[4], gg1[4];
        size_t base = (size_t)n * 128 + lane;
        #pragma unroll
        for (int o = 0; o < 4; o++) {
            a0[o] = hp[o][base];  a1[o] = hp[o][base + 64];
            gg0[o] = gp[o][base]; gg1[o] = gp[o][base + 64];
        }
        float s[4][4], pu[4], pv[4];
        #pragma unroll
        for (int i = 0; i < 4; i++) {
            pu[i] = wred64(uu0 * a0[i] + uu1 * a1[i]);
            pv[i] = wred64(vv0 * a0[i] + vv1 * a1[i]);
            #pragma unroll
            for (int j = 0; j < 4; j++)
                s[i][j] = wred64(a0[i] * gg0[j] + a1[i] * gg1[j]);
        }
        #pragma unroll
        for (int i = 0; i < 4; i++)
            #pragma unroll
            for (int j = 0; j < 4; j++)
                s[i][j] = scale * (s[i][j] + pu[j] + pv[i] + c0v);

        if (lane < 16) {
            int i = lane >> 2, j = lane & 3;
            float m = fmaxf(fmaxf(s[i][0], s[i][1]), fmaxf(s[i][2], s[i][3]));
            float den = expf(s[i][0] - m) + expf(s[i][1] - m) + expf(s[i][2] - m) + expf(s[i][3] - m);
            float attn = expf(s[i][j] - m) / den;
            tacc += logf(attn * rf + 1e-4f);
        }
    }
    __shared__ float accum[4][16];
    if (lane < 16) accum[wid][lane] = tacc;
    __syncthreads();
    if (tid < 16)
        atomicAdd(&Cm[tid], accum[0][tid] + accum[1][tid] + accum[2][tid] + accum[3][tid]);
}

__global__ void k_cvec(const float* __restrict__ Cm, float* __restrict__ c) {
    if (threadIdx.x == 0) {
        float cm[16];
        for (int i = 0; i < 16; i++) cm[i] = Cm[i] / (float)N_NODES;
        float cc[4];
        for (int j = 0; j < 4; j++) cc[j] = 0.5f * (cm[12 + j] + cm[j * 4 + 3]);
        float s = cc[0] + cc[1] + cc[2] + cc[3];
        for (int j = 0; j < 4; j++) c[j] = cc[j] / s;
    }
}

__global__ __launch_bounds__(256) void k_t1(
    const float* __restrict__ h0, const float* __restrict__ h1,
    const float* __restrict__ h2, const float* __restrict__ h3,
    const float* __restrict__ c, float* __restrict__ T1)
{
    float c0 = c[0], c1 = c[1], c2 = c[2], c3 = c[3];
    int stride = gridDim.x * blockDim.x;
    for (int i = blockIdx.x * blockDim.x + threadIdx.x; i < NB4; i += stride) {
        float4 x0 = ((const float4*)h0)[i];
        float4 x1 = ((const float4*)h1)[i];
        float4 x2 = ((const float4*)h2)[i];
        float4 x3 = ((const float4*)h3)[i];
        float4 o;
        o.x = c0 * x0.x + c1 * x1.x + c2 * x2.x + c3 * x3.x;
        o.y = c0 * x0.y + c1 * x1.y + c2 * x2.y + c3 * x3.y;
        o.z = c0 * x0.z + c1 * x1.z + c2 * x2.z + c3 * x3.z;
        o.w = c0 * x0.w + c1 * x1.w + c2 * x2.w + c3 * x3.w;
        ((float4*)T1)[i] = o;
    }
}

/* ---------------- combine + CG init (fused): Tr = elu(bn(T1 + h*dT)); P=X=R=Tr ----------------
   Rv may alias T1v (element-wise in-place). */

__global__ __launch_bounds__(256) void k_combine(
    const float* T1v, const float* __restrict__ M1v, const float* __restrict__ M2v,
    const float* __restrict__ g, const float* __restrict__ b,
    const float* __restrict__ m, const float* __restrict__ v,
    float* __restrict__ Pv, float* __restrict__ Xv, float* Rv,
    float* __restrict__ scal, int* __restrict__ doneArr)
{
    if (blockIdx.x == 0) {
        if (threadIdx.x < 40) scal[threadIdx.x] = 0.f;
        if (threadIdx.x == 40) doneArr[0] = 0;
    }
    int stride = gridDim.x * blockDim.x;
    for (int i = blockIdx.x * blockDim.x + threadIdx.x; i < NB4; i += stride) {
        float4 t1 = ((const float4*)T1v)[i];
        float4 m1 = ((const float4*)M1v)[i];
        float4 m2 = ((const float4*)M2v)[i];
        int chb = (i * 4) & 127;
        float tt[4] = {t1.x, t1.y, t1.z, t1.w};
        float a1[4] = {m1.x, m1.y, m1.z, m1.w};
        float a2[4] = {m2.x, m2.y, m2.z, m2.w};
        float o[4];
        #pragma unroll
        for (int k = 0; k < 4; k++) {
            float cl = fminf(fmaxf(a2[k], -1.f), 1.f);
            float x = tt[k] + HSTEP * (a1[k] + tt[k] * cl);
            int ch = chb + k;
            float xb = (x - m[ch]) * rsqrtf(v[ch] + EPS_BN) * g[ch] + b[ch];
            o[k] = xb > 0.f ? xb : expm1f(xb);
        }
        float4 o4 = make_float4(o[0], o[1], o[2], o[3]);
        ((float4*)Pv)[i] = o4;
        ((float4*)Xv)[i] = o4;
        ((float4*)Rv)[i] = o4;
    }
}

/* pack P -> bf16 mirror (separate pass: Pbf aliases M1 which k_combine reads) */
__global__ __launch_bounds__(256) void k_packbf(const float* __restrict__ P, unsigned* __restrict__ Pbf) {
    int stride = gridDim.x * blockDim.x;
    for (int i = blockIdx.x * blockDim.x + threadIdx.x; i < NB4; i += stride) {
        float4 p = ((const float4*)P)[i];
        ((uint2*)Pbf)[i] = make_uint2(bfpack2(p.x, p.y), bfpack2(p.z, p.w));
    }
}

/* ---------------- CG kernels ---------------- */

/* SpMV + LP + 4 DIRECT dots. Gather operand = bf16 mirror (256B rows, half traffic);
   diagonal term + all dots use full fp32 P. Wave-per-row, 8-unrolled. */
__global__ __launch_bounds__(256) void k_spmv_lp(
    const int* __restrict__ rowptr, const int* __restrict__ ecol, const float* __restrict__ ewt,
    const float* __restrict__ P, const unsigned* __restrict__ Pbf, const float* __restrict__ R,
    const float* __restrict__ Kap,
    float* __restrict__ LP, float* __restrict__ scal, const int* __restrict__ doneArr, int it)
{
    if (doneArr[it]) return;
    int tid = threadIdx.x;
    int lane = tid & 63, wid = tid >> 6;
    float2 kd2 = ((const float2*)Kap)[lane];
    kd2.x = fminf(fmaxf(kd2.x, 0.f), 1.f);
    kd2.y = fminf(fmaxf(kd2.y, 0.f), 1.f);
    const float2* P2 = (const float2*)P;
    const float2* R2 = (const float2*)R;
    float2* LP2 = (float2*)LP;

    float pPLP = 0.f, pRR = 0.f, pRLP = 0.f, pLPLP = 0.f;
    int totalWaves = gridDim.x * 4;
    for (int r = blockIdx.x * 4 + wid; r < N_NODES; r += totalWaves) {
        int e0 = rowptr[r], e1 = rowptr[r + 1];
        float ax = 0.f, ay = 0.f;
        int e = e0;
        for (; e + 8 <= e1; e += 8) {
            int   c0 = ecol[e],     c1 = ecol[e + 1], c2 = ecol[e + 2], c3 = ecol[e + 3];
            int   c4 = ecol[e + 4], c5 = ecol[e + 5], c6 = ecol[e + 6], c7 = ecol[e + 7];
            float w0 = ewt[e],     w1 = ewt[e + 1], w2 = ewt[e + 2], w3 = ewt[e + 3];
            float w4 = ewt[e + 4], w5 = ewt[e + 5], w6 = ewt[e + 6], w7 = ewt[e + 7];
            unsigned q0 = Pbf[(size_t)c0 * 64 + lane];
            unsigned q1 = Pbf[(size_t)c1 * 64 + lane];
            unsigned q2 = Pbf[(size_t)c2 * 64 + lane];
            unsigned q3 = Pbf[(size_t)c3 * 64 + lane];
            unsigned q4 = Pbf[(size_t)c4 * 64 + lane];
            unsigned q5 = Pbf[(size_t)c5 * 64 + lane];
            unsigned q6 = Pbf[(size_t)c6 * 64 + lane];
            unsigned q7 = Pbf[(size_t)c7 * 64 + lane];
            float2 p0 = bfget2(q0), p1 = bfget2(q1), p2 = bfget2(q2), p3 = bfget2(q3);
            float2 p4 = bfget2(q4), p5 = bfget2(q5), p6 = bfget2(q6), p7 = bfget2(q7);
            ax += w0 * p0.x + w1 * p1.x + w2 * p2.x + w3 * p3.x
                + w4 * p4.x + w5 * p5.x + w6 * p6.x + w7 * p7.x;
            ay += w0 * p0.y + w1 * p1.y + w2 * p2.y + w3 * p3.y
                + w4 * p4.y + w5 * p5.y + w6 * p6.y + w7 * p7.y;
        }
        for (; e < e1; ++e) {
            int c = ecol[e]; float w = ewt[e];
            float2 p = bfget2(Pbf[(size_t)c * 64 + lane]);
            ax += w * p.x; ay += w * p.y;
        }
        size_t idx = (size_t)r * 64 + lane;
        float2 pv = P2[idx];
        float2 rv = R2[idx];
        float2 lp;
        lp.x = pv.x + HSTEP * (kd2.x * (pv.x + ax));
        lp.y = pv.y + HSTEP * (kd2.y * (pv.y + ay));
        LP2[idx] = lp;
        pPLP  += pv.x * lp.x + pv.y * lp.y;
        pRR   += rv.x * rv.x + rv.y * rv.y;
        pRLP  += rv.x * lp.x + rv.y * lp.y;
        pLPLP += lp.x * lp.x + lp.y * lp.y;
    }
    pPLP = wred64(pPLP); pRR = wred64(pRR); pRLP = wred64(pRLP); pLPLP = wred64(pLPLP);
    __shared__ float red[16];
    if (lane == 0) { red[wid] = pPLP; red[4 + wid] = pRR; red[8 + wid] = pRLP; red[12 + wid] = pLPLP; }
    __syncthreads();
    if (tid == 0) {
        atomicAdd(&scal[SLOT_PLP  + it], red[0] + red[1] + red[2] + red[3]);
        atomicAdd(&scal[SLOT_RR   + it], red[4] + red[5] + red[6] + red[7]);
        atomicAdd(&scal[SLOT_RLP  + it], red[8] + red[9] + red[10] + red[11]);
        atomicAdd(&scal[SLOT_LPLP + it], red[12] + red[13] + red[14] + red[15]);
    }
}

/* Fused X/R/P update (+ bf16 mirror of new P). nr algebraic within iteration only;
   next iteration's RR is recomputed directly from R in k_spmv_lp. */
__global__ __launch_bounds__(256) void k_upd(
    float* __restrict__ X, float* __restrict__ P, const float* __restrict__ LP,
    float* __restrict__ R, unsigned* __restrict__ Pbf,
    const float* __restrict__ scal, int* __restrict__ doneArr, int it)
{
    int d = doneArr[it];
    float RR   = scal[SLOT_RR + it];
    float PLP  = scal[SLOT_PLP + it];
    float RLP  = scal[SLOT_RLP + it];
    float LPLP = scal[SLOT_LPLP + it];
    float alpha = RR / (PLP + 1e-6f);
    float nr = RR - 2.f * alpha * RLP + alpha * alpha * LPLP;
    int d2 = d || (nr < 1e-5f);
    if (blockIdx.x == 0 && threadIdx.x == 0) doneArr[it + 1] = d2;
    if (d) return;
    float beta = nr / (RR + 1e-6f);
    int stride = gridDim.x * blockDim.x;
    for (int i = blockIdx.x * blockDim.x + threadIdx.x; i < NB4; i += stride) {
        float4 x = ((const float4*)X)[i];
        float4 p = ((const float4*)P)[i];
        float4 lp = ((const float4*)LP)[i];
        float4 r = ((const float4*)R)[i];
        x.x += alpha * p.x; x.y += alpha * p.y; x.z += alpha * p.z; x.w += alpha * p.w;
        r.x -= alpha * lp.x; r.y -= alpha * lp.y; r.z -= alpha * lp.z; r.w -= alpha * lp.w;
        ((float4*)X)[i] = x;
        ((float4*)R)[i] = r;
        if (!d2) {
            p.x = r.x + beta * p.x; p.y = r.y + beta * p.y;
            p.z = r.z + beta * p.z; p.w = r.w + beta * p.w;
            ((float4*)P)[i] = p;
            ((uint2*)Pbf)[i] = make_uint2(bfpack2(p.x, p.y), bfpack2(p.z, p.w));
        }
    }
}

/* ---------------- host ---------------- */

extern "C" void kernel_launch(void* const* d_in, const int* in_sizes, int n_in,
                              void* d_out, int out_size, void* d_ws, size_t ws_size,
                              hipStream_t stream) {
    (void)in_sizes; (void)n_in; (void)out_size; (void)ws_size;

    const float* T      = (const float*)d_in[0];
    const int*   EI     = (const int*)d_in[1];
    const float* KopenW = (const float*)d_in[2];
    const float* Kopenb = (const float*)d_in[3];
    const float* bnOg   = (const float*)d_in[4];
    const float* bnOb   = (const float*)d_in[5];
    const float* bnOm   = (const float*)d_in[6];
    const float* bnOv   = (const float*)d_in[7];
    const float* convW  = (const float*)d_in[8];
    const float* convb  = (const float*)d_in[9];
    const float* bnAg   = (const float*)d_in[10];
    const float* bnAb   = (const float*)d_in[11];
    const float* bnAm   = (const float*)d_in[12];
    const float* bnAv   = (const float*)d_in[13];
    const float* Wq     = (const float*)d_in[14];
    const float* bq     = (const float*)d_in[15];
    const float* Wk     = (const float*)d_in[16];
    const float* bk     = (const float*)d_in[17];
    const float* mha    = (const float*)d_in[18];
    const float* KR1W   = (const float*)d_in[19];
    const float* KR1b   = (const float*)d_in[20];
    const float* KR2W   = (const float*)d_in[21];
    const float* KR2b   = (const float*)d_in[22];
    const float* KRU0W  = (const float*)d_in[23];
    const float* KRU0b  = (const float*)d_in[24];
    const float* bng    = (const float*)d_in[25];
    const float* bnbb   = (const float*)d_in[26];
    const float* bnm    = (const float*)d_in[27];
    const float* bnv    = (const float*)d_in[28];
    const float* Kappa  = (const float*)d_in[29];
    const float* KcloseW = (const float*)d_in[30];
    const float* Kcloseb = (const float*)d_in[31];

    const int* row = EI;
    const int* col = EI + N_EDGES;

    char* ws = (char*)d_ws;
    size_t off = 0;
    auto alloc = [&](size_t bytes) -> void* {
        void* p = ws + off;
        off += (bytes + 255) & ~(size_t)255;
        return p;
    };

    float* B[10];
    for (int i = 0; i < 10; i++) B[i] = (float*)alloc((size_t)NB * 4);
    int*   ecol   = (int*)alloc((size_t)N_EDGES * 4);
    float* ewt    = (float*)alloc((size_t)N_EDGES * 4);
    int*   rowptr = (int*)alloc((size_t)(N_NODES + 1) * 4);
    int*   cursor = (int*)alloc((size_t)N_NODES * 4);
    int*   deg    = (int*)alloc((size_t)N_NODES * 4);
    float* dinv   = (float*)alloc((size_t)N_NODES * 4);
    int*   blksum = (int*)alloc(256 * 4);
    int*   blkoff = (int*)alloc(256 * 4);
    float* Mmat   = (float*)alloc(128 * 128 * 4);
    float* uvec   = (float*)alloc(512);
    float* vvec   = (float*)alloc(512);
    float* c0s    = (float*)alloc(256);
    float* Cm     = (float*)alloc(256);
    float* cvec   = (float*)alloc(256);
    float* scal   = (float*)alloc(256);
    int*   doneA  = (int*)alloc(256);

    float* TH = B[0];
    float* Z  = B[1];
    float* XB[4] = {B[2], B[3], B[4], B[5]};
    float* G[4]  = {B[6], B[7], B[8], B[9]};
    float* M1 = G[0], *M2 = G[1], *T1 = G[3];
    float* LPb = G[1];   /* aliases M2: M2 consumed in combine before LP writes */
    float* Pb  = G[2];
    float* Rb  = G[3];   /* aliases T1: combine writes R in-place over T1 */
    /* bf16 mirror of P lives in M1's buffer (12.8MB of 25.6MB): M1 is dead during CG.
       Written by k_packbf (after combine) and k_upd; overwritten by next layer's GEMMs. */
    unsigned* Pbf = (unsigned*)G[0];

    /* CSR build */
    k_zero_i32<<<196, 256, 0, stream>>>(deg, N_NODES);
    k_count<<<(N_EDGES + 255) / 256, 256, 0, stream>>>(row, col, deg);
    k_scan1<<<SCAN_BLOCKS, 256, 0, stream>>>(deg, rowptr, blksum);
    k_scan2<<<1, 256, 0, stream>>>(blksum, blkoff);
    k_scan3<<<SCAN_BLOCKS, 256, 0, stream>>>(deg, blkoff, rowptr, dinv, cursor);
    k_scatter<<<(N_EDGES + 255) / 256, 256, 0, stream>>>(row, col, dinv, cursor, ecol, ewt);

    /* attention precompute */
    k_mmat<<<128, 128, 0, stream>>>(Wq, Wk, Mmat);
    k_uv<<<1, 128, 0, stream>>>(Wq, Wk, bq, bk, uvec, vvec, c0s);

    const int GEMM_GRID = (N_NODES + 63) / 64;

    /* opening */
    k_gemm128<<<GEMM_GRID, 256, 0, stream>>>(T, KopenW, Kopenb, TH, N_NODES, 1, 0, bnOg, bnOb, bnOm, bnOv);
    k_gemm128<<<GEMM_GRID, 256, 0, stream>>>(TH, convW, convb, Z, N_NODES, 2, 0, bnAg, bnAb, bnAm, bnAv);

    const float* hist[4] = {Z, Z, Z, Z};

    for (int jj = 0; jj < NLAYERS; jj++) {
        /* unique history slots */
        const float* uq[4];
        int nu = 0, gi[4];
        for (int i = 0; i < 4; i++) {
            int f = -1;
            for (int k = 0; k < nu; k++) if (uq[k] == hist[i]) f = k;
            if (f < 0) { uq[nu] = hist[i]; f = nu; nu++; }
            gi[i] = f;
        }
        for (int u = 0; u < nu; u++)
            k_gemm128<<<GEMM_GRID, 256, 0, stream>>>(uq[u], Mmat, nullptr, G[u], N_NODES, 0, 0,
                                                     nullptr, nullptr, nullptr, nullptr);
        k_zero16<<<1, 64, 0, stream>>>(Cm);
        k_attn<<<ATTN_BLOCKS, 256, 0, stream>>>(hist[0], hist[1], hist[2], hist[3],
                                                G[gi[0]], G[gi[1]], G[gi[2]], G[gi[3]],
                                                uvec, vvec, c0s, mha, Cm);
        k_cvec<<<1, 64, 0, stream>>>(Cm, cvec);
        k_t1<<<EW_BLOCKS, 256, 0, stream>>>(hist[0], hist[1], hist[2], hist[3], cvec, T1);

        k_gemm128<<<GEMM_GRID, 256, 0, stream>>>(T1, KR1W + (size_t)jj * 16384, KR1b + jj * 128, M1,
                                                 N_NODES, 0, 0, nullptr, nullptr, nullptr, nullptr);
        k_gemm128<<<GEMM_GRID, 256, 0, stream>>>(TH, KRU0W + (size_t)jj * 16384, KRU0b + jj * 128, M1,
                                                 N_NODES, 0, 1, nullptr, nullptr, nullptr, nullptr);
        k_gemm128<<<GEMM_GRID, 256, 0, stream>>>(T1, KR2W + (size_t)jj * 16384, KR2b + jj * 128, M2,
                                                 N_NODES, 0, 0, nullptr, nullptr, nullptr, nullptr);
        /* combine + CG init: P = X = R = Tr (R in-place over T1) */
        k_combine<<<EW_BLOCKS, 256, 0, stream>>>(T1, M1, M2,
                                                 bng + jj * 128, bnbb + jj * 128, bnm + jj * 128, bnv + jj * 128,
                                                 Pb, XB[jj], Rb, scal, doneA);
        /* bf16 mirror (M1 is dead from here until next layer) */
        k_packbf<<<EW_BLOCKS, 256, 0, stream>>>(Pb, Pbf);

        for (int it = 0; it < CG_ITERS; it++) {
            k_spmv_lp<<<SPMV_BLOCKS, 256, 0, stream>>>(rowptr, ecol, ewt, Pb, Pbf, Rb, Kappa + jj * 128,
                                                       LPb, scal, doneA, it);
            k_upd<<<EW_BLOCKS, 256, 0, stream>>>(XB[jj], Pb, LPb, Rb, Pbf, scal, doneA, it);
        }

        hist[0] = hist[1]; hist[1] = hist[2]; hist[2] = hist[3]; hist[3] = XB[jj];
    }

    k_close<<<(N_NODES + 255) / 256, 256, 0, stream>>>(XB[3], KcloseW, Kcloseb, (float*)d_out);
}